// Round 2
// baseline (2070.654 us; speedup 1.0000x reference)
//
#include <hip/hip_runtime.h>
#include <hip/hip_bf16.h>

#define S_LEN 1024
#define BATCH 8
#define HD 512
#define FFD 2048
#define NHEAD 4
#define NBLK 3
#define NTOK 128

typedef __bf16 bf16_t;
typedef __bf16 bf16x8_t __attribute__((ext_vector_type(8)));
typedef float f32x4_t __attribute__((ext_vector_type(4)));

#define TM 128
#define TN 128
#define BKK 64
#define LPAD 8

// ---------------- GEMM: C = alpha * A @ Bt^T (+bias) (+relu) ----------------
// A: [M,K] bf16 row-major (lda). Bt: [N,K] bf16 row-major (ldb)  (i.e. B^T form).
// C row addressing: ro = coff + (row>>msub_shift)*msub_stride + (row&mask)*ldc
// batch z: A += z*sA, Bt += z*sB, bias += z*sBias,
//          coff = (z>>zshift)*sC_hi + (z&((1<<zshift)-1))*sC_lo
template<bool OUT_BF16, bool BIAS, bool RELU, bool CSKIP, bool CKLIM>
__global__ void gemm_bt_kernel(const bf16_t* __restrict__ A,
                               const bf16_t* __restrict__ Bt,
                               const float* __restrict__ bias,
                               void* __restrict__ Cv,
                               int M, int N, int K,
                               int lda, int ldb, int ldc,
                               long long sA, long long sB, long long sBias,
                               int zshift, long long sC_hi, long long sC_lo,
                               int msub_shift, long long msub_stride,
                               float alpha)
{
  const int zb = blockIdx.z;
  const int m0 = blockIdx.x * TM;
  const int n0 = blockIdx.y * TN;
  if (CSKIP && n0 > m0 + TM - 1) return;   // fully-masked causal tile
  int kend = K;
  if (CKLIM) { int ke = m0 + TM; kend = ke < K ? ke : K; }

  const bf16_t* Az = A + (long long)zb * sA;
  const bf16_t* Bz = Bt + (long long)zb * sB;
  const long long coff = ((long long)(zb >> zshift)) * sC_hi
                       + ((long long)(zb & ((1 << zshift) - 1))) * sC_lo;

  __shared__ __align__(16) bf16_t As[TM][BKK + LPAD];
  __shared__ __align__(16) bf16_t Bs[TN][BKK + LPAD];

  const int tid = threadIdx.x;
  const int w = tid >> 6;
  const int lane = tid & 63;
  const int wm = (w >> 1) * 64;
  const int wn = (w & 1) * 64;
  const int fr = lane & 15;
  const int fg = lane >> 4;

  const int srow = tid >> 1;          // 0..127
  const int scol = (tid & 1) * 32;    // 0 or 32 (elements)

  f32x4_t acc[4][4];
  #pragma unroll
  for (int i = 0; i < 4; ++i)
    #pragma unroll
    for (int j = 0; j < 4; ++j)
      acc[i][j] = (f32x4_t){0.f, 0.f, 0.f, 0.f};

  const bf16_t* gA = Az + (long long)(m0 + srow) * lda + scol;
  const bf16_t* gB = Bz + (long long)(n0 + srow) * ldb + scol;

  for (int k0 = 0; k0 < kend; k0 += BKK) {
    __syncthreads();
    {
      const uint4* pa = (const uint4*)(gA + k0);
      const uint4* pb = (const uint4*)(gB + k0);
      uint4 a0 = pa[0], a1 = pa[1], a2 = pa[2], a3 = pa[3];
      uint4 b0 = pb[0], b1 = pb[1], b2 = pb[2], b3 = pb[3];
      uint4* la = (uint4*)&As[srow][scol];
      uint4* lb = (uint4*)&Bs[srow][scol];
      la[0] = a0; la[1] = a1; la[2] = a2; la[3] = a3;
      lb[0] = b0; lb[1] = b1; lb[2] = b2; lb[3] = b3;
    }
    __syncthreads();
    #pragma unroll
    for (int kc = 0; kc < 2; ++kc) {
      bf16x8_t af[4], bfr[4];
      #pragma unroll
      for (int i = 0; i < 4; ++i)
        af[i] = *(const bf16x8_t*)&As[wm + i*16 + fr][kc*32 + fg*8];
      #pragma unroll
      for (int j = 0; j < 4; ++j)
        bfr[j] = *(const bf16x8_t*)&Bs[wn + j*16 + fr][kc*32 + fg*8];
      #pragma unroll
      for (int i = 0; i < 4; ++i)
        #pragma unroll
        for (int j = 0; j < 4; ++j)
          acc[i][j] = __builtin_amdgcn_mfma_f32_16x16x32_bf16(af[i], bfr[j], acc[i][j], 0, 0, 0);
    }
  }

  #pragma unroll
  for (int i = 0; i < 4; ++i) {
    #pragma unroll
    for (int e = 0; e < 4; ++e) {
      const int row = m0 + wm + i*16 + fg*4 + e;
      const long long ro = coff
        + ((long long)(row >> msub_shift)) * msub_stride
        + (long long)(row & ((1 << msub_shift) - 1)) * (long long)ldc;
      #pragma unroll
      for (int j = 0; j < 4; ++j) {
        const int col = n0 + wn + j*16 + fr;
        float v = acc[i][j][e] * alpha;
        if (BIAS) v += bias[(long long)zb * sBias + col];
        if (RELU) v = v > 0.f ? v : 0.f;
        if (OUT_BF16) ((bf16_t*)Cv)[ro + col] = (bf16_t)v;
        else          ((float*)Cv)[ro + col]  = v;
      }
    }
  }
}

// ---------------- transpose (+cast to bf16): out[C][R] = in[R][C] ----------------
template<typename TIN>
__global__ void transpose_kernel(const TIN* __restrict__ in, bf16_t* __restrict__ out,
                                 int R, int C, long long sIn, long long sOut)
{
  __shared__ float tile[32][33];
  const long long zi = (long long)blockIdx.z * sIn;
  const long long zo = (long long)blockIdx.z * sOut;
  const int c0 = blockIdx.x * 32, r0 = blockIdx.y * 32;
  const int tx = threadIdx.x, ty = threadIdx.y;  // 32 x 8
  #pragma unroll
  for (int i = 0; i < 4; ++i) {
    int r = r0 + ty + i*8;
    tile[ty + i*8][tx] = (float)in[zi + (long long)r * C + c0 + tx];
  }
  __syncthreads();
  #pragma unroll
  for (int i = 0; i < 4; ++i) {
    int c = c0 + ty + i*8;
    out[zo + (long long)c * R + r0 + tx] = (bf16_t)tile[tx][ty + i*8];
  }
}

// ---------------- f32 -> bf16 flat convert ----------------
__global__ void convert_kernel(const float* __restrict__ in, bf16_t* __restrict__ out, long long n)
{
  long long i = (long long)blockIdx.x * blockDim.x + threadIdx.x;
  long long stride = (long long)gridDim.x * blockDim.x;
  for (; i < n; i += stride) out[i] = (bf16_t)in[i];
}

// ---------------- diagnostic fill ----------------
__global__ void fill_kernel(float* __restrict__ out, long long n, float v)
{
  long long i = (long long)blockIdx.x * blockDim.x + threadIdx.x;
  long long stride = (long long)gridDim.x * blockDim.x;
  for (; i < n; i += stride) out[i] = v;
}

// ---------------- positions: pos = cumsum(mask) - 1 ----------------
__global__ void pos_kernel(const int* __restrict__ mask, float* __restrict__ pos)
{
  __shared__ float scn[S_LEN];
  const int b = blockIdx.x, t = threadIdx.x;
  scn[t] = (float)(mask[b * S_LEN + t] != 0);
  __syncthreads();
  for (int off = 1; off < S_LEN; off <<= 1) {
    float add = (t >= off) ? scn[t - off] : 0.f;
    __syncthreads();
    scn[t] += add;
    __syncthreads();
  }
  pos[b * S_LEN + t] = scn[t] - 1.0f;
}

// ---------------- embedding + positional encoding ----------------
__global__ void embed_kernel(const int* __restrict__ ids, const int* __restrict__ mask,
                             const float* __restrict__ pos, const float* __restrict__ emb,
                             float* __restrict__ x, bf16_t* __restrict__ xb)
{
  const int idx = blockIdx.x * 256 + threadIdx.x;   // over B*S*256 half-dim pairs
  const int i = idx & 255;
  const int bs = idx >> 8;
  const int id = ids[bs];
  const float m = (float)(mask[bs] != 0);
  const float p = pos[bs];
  const float dv = __expf(-(float)(2 * i) * (9.210340371976184f / (float)HD));
  const float sv = __sinf(p * dv) * m;
  const float e0 = emb[id * HD + 2*i], e1 = emb[id * HD + 2*i + 1];
  const float x0 = e0 + sv, x1 = e1 + sv;
  x[(long long)bs * HD + 2*i]     = x0;
  x[(long long)bs * HD + 2*i + 1] = x1;
  xb[(long long)bs * HD + 2*i]     = (bf16_t)x0;
  xb[(long long)bs * HD + 2*i + 1] = (bf16_t)x1;
}

// ---------------- causal masked softmax row kernel, f32 scores -> bf16 P ----------------
__global__ void softmax_kernel(const float* __restrict__ sc, bf16_t* __restrict__ P,
                               const int* __restrict__ mask, int pair0)
{
  const int s = blockIdx.x;
  const int pz = blockIdx.y;
  const int pair = pair0 + pz;
  const int b = pair >> 2;
  const float* src = sc + ((long long)pz * S_LEN + s) * S_LEN;
  bf16_t* dst = P + ((long long)pz * S_LEN + s) * S_LEN;
  const bool qvalid = mask[b * S_LEN + s] != 0;
  const int tid = threadIdx.x;
  __shared__ float red[4];

  float mx = -INFINITY;
  for (int t = tid; t <= s; t += 256)
    if (mask[b * S_LEN + t] != 0) mx = fmaxf(mx, src[t]);
  #pragma unroll
  for (int o = 32; o; o >>= 1) mx = fmaxf(mx, __shfl_xor(mx, o));
  if ((tid & 63) == 0) red[tid >> 6] = mx;
  __syncthreads();
  mx = fmaxf(fmaxf(red[0], red[1]), fmaxf(red[2], red[3]));
  __syncthreads();

  float sum = 0.f;
  for (int t = tid; t <= s; t += 256)
    if (mask[b * S_LEN + t] != 0) sum += __expf(src[t] - mx);
  #pragma unroll
  for (int o = 32; o; o >>= 1) sum += __shfl_xor(sum, o);
  if ((tid & 63) == 0) red[tid >> 6] = sum;
  __syncthreads();
  sum = red[0] + red[1] + red[2] + red[3];

  const float inv = (qvalid && sum > 0.f) ? 1.f / sum : 0.f;
  for (int t = tid; t < S_LEN; t += 256) {
    float pv = 0.f;
    if (inv != 0.f && t <= s && mask[b * S_LEN + t] != 0)
      pv = __expf(src[t] - mx) * inv;
    dst[t] = (bf16_t)pv;
  }
}

// ---------------- layernorm: x = LN(x + add); also emit bf16 copy ----------------
__global__ void ln_kernel(float* __restrict__ x, const float* __restrict__ add,
                          const float* __restrict__ g, const float* __restrict__ b,
                          bf16_t* __restrict__ xb)
{
  __shared__ float red[4];
  const long long row = blockIdx.x;
  const int tid = threadIdx.x;  // 256, 2 elems each
  float v0 = x[row * HD + tid]       + add[row * HD + tid];
  float v1 = x[row * HD + tid + 256] + add[row * HD + tid + 256];
  float s = v0 + v1;
  #pragma unroll
  for (int o = 32; o; o >>= 1) s += __shfl_xor(s, o);
  if ((tid & 63) == 0) red[tid >> 6] = s;
  __syncthreads();
  const float mu = (red[0] + red[1] + red[2] + red[3]) * (1.f / (float)HD);
  __syncthreads();
  const float d0 = v0 - mu, d1 = v1 - mu;
  float q = d0 * d0 + d1 * d1;
  #pragma unroll
  for (int o = 32; o; o >>= 1) q += __shfl_xor(q, o);
  if ((tid & 63) == 0) red[tid >> 6] = q;
  __syncthreads();
  const float var = (red[0] + red[1] + red[2] + red[3]) * (1.f / (float)HD);
  const float inv = rsqrtf(var + 1e-5f);
  const float y0 = d0 * inv * g[tid]       + b[tid];
  const float y1 = d1 * inv * g[tid + 256] + b[tid + 256];
  x[row * HD + tid]       = y0;
  x[row * HD + tid + 256] = y1;
  xb[row * HD + tid]       = (bf16_t)y0;
  xb[row * HD + tid + 256] = (bf16_t)y1;
}

extern "C" void kernel_launch(void* const* d_in, const int* in_sizes, int n_in,
                              void* d_out, int out_size, void* d_ws, size_t ws_size,
                              hipStream_t stream)
{
  (void)in_sizes; (void)n_in;
  const int*   ids   = (const int*)d_in[0];
  const int*   amask = (const int*)d_in[1];
  const float* emb   = (const float*)d_in[2];
  const float* wq    = (const float*)d_in[3];
  const float* wk    = (const float*)d_in[4];
  const float* wv    = (const float*)d_in[5];
  const float* wo_w  = (const float*)d_in[6];
  const float* wo_b  = (const float*)d_in[7];
  const float* ln1_g = (const float*)d_in[8];
  const float* ln1_b = (const float*)d_in[9];
  const float* ff1_w = (const float*)d_in[10];
  const float* ff1_b = (const float*)d_in[11];
  const float* ff2_w = (const float*)d_in[12];
  const float* ff2_b = (const float*)d_in[13];
  const float* ln2_g = (const float*)d_in[14];
  const float* ln2_b = (const float*)d_in[15];
  const float* lm_w  = (const float*)d_in[16];

  const long long MROW = (long long)BATCH * S_LEN;   // 8192
  const size_t MBc = 1ull << 20;
  char* p = (char*)d_ws;
  auto alloc = [&](size_t bytes) { char* r = p; p += (bytes + 255) & ~(size_t)255; return r; };

  // persistent buffers (~68 MB)
  float*  x    = (float*) alloc(MROW * HD * 4);                // 16 MB
  bf16_t* xb   = (bf16_t*)alloc(MROW * HD * 2);                // 8 MB
  bf16_t* ob   = (bf16_t*)alloc(MROW * (NHEAD*HD) * 2);        // 32 MB
  bf16_t* wqT  = (bf16_t*)alloc(4LL * HD * HD * 2);            // 2 MB (current layer)
  bf16_t* wkT  = (bf16_t*)alloc(4LL * HD * HD * 2);
  bf16_t* wvT  = (bf16_t*)alloc(4LL * HD * HD * 2);
  bf16_t* woT  = (bf16_t*)alloc((long long)HD * FFD * 2);
  bf16_t* wff1 = (bf16_t*)alloc((long long)FFD * HD * 2);
  bf16_t* wff2 = (bf16_t*)alloc((long long)HD * FFD * 2);
  bf16_t* lmT  = (bf16_t*)alloc((long long)NTOK * HD * 2);
  float*  pos  = (float*) alloc(MROW * 4);

  const size_t used = (size_t)(p - (char*)d_ws);
  const size_t rem  = ws_size > used ? ws_size - used : 0;

  // attention pair-chunk size P: per pair needs 3x1MB (q,k,v) + 1MB (vT) + 4MB (sc f32) + 2MB (P bf16)
  int P = 0;
  if      (rem >= 80 * MBc) P = 8;
  else if (rem >= 48 * MBc) P = 4;   // FF phase needs 48 MB regardless (tmp 16 + ffb 32)
  if (P == 0) {
    // plan does not fit: report ws_size (in MB) through the absmax channel
    fill_kernel<<<1024, 256, 0, stream>>>((float*)d_out, (long long)out_size,
                                          (float)(ws_size >> 20));
    return;
  }

  // region A (aliased): attention chunk buffers  OR  [tmp f32 16MB | ffb 32MB]
  char* A = p;
  const long long pairE = (long long)S_LEN * HD;       // elements per pair (q/k/v/vT)
  bf16_t* qc  = (bf16_t*)A;
  bf16_t* kc  = qc  + (long long)P * pairE;
  bf16_t* vc  = kc  + (long long)P * pairE;
  bf16_t* vTc = vc  + (long long)P * pairE;
  float*  scb = (float*)(vTc + (long long)P * pairE);
  bf16_t* Pb  = (bf16_t*)(scb + (long long)P * S_LEN * S_LEN);
  float*  tmp = (float*)A;                              // FF phase
  bf16_t* ffb = (bf16_t*)(A + 16 * MBc);

  const dim3 tb(32, 8);
  transpose_kernel<float><<<dim3(4,16,1), tb, 0, stream>>>(lm_w, lmT, HD, NTOK, 0, 0);
  pos_kernel<<<BATCH, S_LEN, 0, stream>>>(amask, pos);
  embed_kernel<<<8192, 256, 0, stream>>>(ids, amask, pos, emb, x, xb);

  const int nch = 32 / P;         // chunks of (b,head) pairs
  const int bpc = P / NHEAD;      // batches per chunk

  for (int l = 0; l < NBLK; ++l) {
    // per-layer weight prep (bf16, B^T form)
    transpose_kernel<float><<<dim3(16,16,4), tb, 0, stream>>>(
      wq + (long long)l*NHEAD*HD*HD, wqT, HD, HD, (long long)HD*HD, (long long)HD*HD);
    transpose_kernel<float><<<dim3(16,16,4), tb, 0, stream>>>(
      wk + (long long)l*NHEAD*HD*HD, wkT, HD, HD, (long long)HD*HD, (long long)HD*HD);
    transpose_kernel<float><<<dim3(16,16,4), tb, 0, stream>>>(
      wv + (long long)l*NHEAD*HD*HD, wvT, HD, HD, (long long)HD*HD, (long long)HD*HD);
    transpose_kernel<float><<<dim3(16,64,1), tb, 0, stream>>>(
      wo_w + (long long)l*FFD*HD, woT, FFD, HD, 0, 0);
    convert_kernel<<<1024, 256, 0, stream>>>(ff1_w + (long long)l*FFD*HD, wff1, (long long)FFD*HD);
    convert_kernel<<<1024, 256, 0, stream>>>(ff2_w + (long long)l*HD*FFD, wff2, (long long)HD*FFD);

    for (int c = 0; c < nch; ++c) {
      const int b0 = c * bpc;               // first batch of chunk
      const int pair0 = b0 * NHEAD;         // first global pair
      const int Mch = bpc * S_LEN;          // rows of x in chunk

      // q/k/v projections for this chunk's batches, z = head
      gemm_bt_kernel<true,false,false,false,false><<<dim3(Mch/TM,4,4),256,0,stream>>>(
        xb + (long long)b0*S_LEN*HD, wqT, nullptr, qc, Mch, HD, HD, HD, HD, HD,
        0, (long long)HD*HD, 0,
        30, 0, (long long)S_LEN*HD,
        10, (long long)NHEAD*S_LEN*HD, 1.f);
      gemm_bt_kernel<true,false,false,false,false><<<dim3(Mch/TM,4,4),256,0,stream>>>(
        xb + (long long)b0*S_LEN*HD, wkT, nullptr, kc, Mch, HD, HD, HD, HD, HD,
        0, (long long)HD*HD, 0,
        30, 0, (long long)S_LEN*HD,
        10, (long long)NHEAD*S_LEN*HD, 1.f);
      gemm_bt_kernel<true,false,false,false,false><<<dim3(Mch/TM,4,4),256,0,stream>>>(
        xb + (long long)b0*S_LEN*HD, wvT, nullptr, vc, Mch, HD, HD, HD, HD, HD,
        0, (long long)HD*HD, 0,
        30, 0, (long long)S_LEN*HD,
        10, (long long)NHEAD*S_LEN*HD, 1.f);

      // v^T per pair for PV gemm
      transpose_kernel<bf16_t><<<dim3(16,32,P), tb, 0, stream>>>(
        vc, vTc, S_LEN, HD, (long long)S_LEN*HD, (long long)HD*S_LEN);

      // scores = q @ k^T / sqrt(512)   (causal tile skip)
      gemm_bt_kernel<false,false,false,true,false><<<dim3(8,8,P),256,0,stream>>>(
        qc, kc, nullptr, scb,
        S_LEN, S_LEN, HD, HD, HD, S_LEN,
        (long long)S_LEN*HD, (long long)S_LEN*HD, 0,
        30, 0, (long long)S_LEN*S_LEN,
        30, 0, 0.044194173824159216f);
      softmax_kernel<<<dim3(S_LEN,P),256,0,stream>>>(scb, Pb, amask, pair0);
      // o[b,s,h*512+d] = P @ v   (causal k-limit)
      gemm_bt_kernel<true,false,false,false,true><<<dim3(8,4,P),256,0,stream>>>(
        Pb, vTc, nullptr,
        ob + (long long)b0*S_LEN*(NHEAD*HD),
        S_LEN, HD, S_LEN, S_LEN, S_LEN, NHEAD*HD,
        (long long)S_LEN*S_LEN, (long long)HD*S_LEN, 0,
        2, (long long)S_LEN*NHEAD*HD, HD,
        30, 0, 1.f);
    }

    // mh = o @ wo + wo_b  -> tmp (f32)
    gemm_bt_kernel<false,true,false,false,false><<<dim3(64,4,1),256,0,stream>>>(
      ob, woT, wo_b + l*HD, tmp,
      (int)MROW, HD, NHEAD*HD, NHEAD*HD, NHEAD*HD, HD,
      0, 0, 0, 30, 0, 0, 30, 0, 1.f);
    ln_kernel<<<8192,256,0,stream>>>(x, tmp, ln1_g + l*HD, ln1_b + l*HD, xb);

    // ff1: relu(xb @ ff1^T + b1) -> ffb (bf16)
    gemm_bt_kernel<true,true,true,false,false><<<dim3(64,16,1),256,0,stream>>>(
      xb, wff1, ff1_b + l*FFD, ffb,
      (int)MROW, FFD, HD, HD, HD, FFD,
      0, 0, 0, 30, 0, 0, 30, 0, 1.f);
    // ff2 -> tmp (f32)
    gemm_bt_kernel<false,true,false,false,false><<<dim3(64,4,1),256,0,stream>>>(
      ffb, wff2, ff2_b + l*HD, tmp,
      (int)MROW, HD, FFD, FFD, FFD, HD,
      0, 0, 0, 30, 0, 0, 30, 0, 1.f);
    ln_kernel<<<8192,256,0,stream>>>(x, tmp, ln2_g + l*HD, ln2_b + l*HD, xb);
  }

  // lm head -> d_out (f32)
  gemm_bt_kernel<false,false,false,false,false><<<dim3(64,1,1),256,0,stream>>>(
    xb, lmT, nullptr, (float*)d_out,
    (int)MROW, NTOK, HD, HD, HD, NTOK,
    0, 0, 0, 30, 0, 0, 30, 0, 1.f);
}

// Round 3
// 1346.090 us; speedup vs baseline: 1.5383x; 1.5383x over previous
//
#include <hip/hip_runtime.h>
#include <hip/hip_bf16.h>

#define S_LEN 1024
#define BATCH 8
#define HD 512
#define FFD 2048
#define NHEAD 4
#define NBLK 3
#define NTOK 128

typedef __bf16 bf16_t;
typedef __bf16 bf16x8_t __attribute__((ext_vector_type(8)));
typedef float f32x4_t __attribute__((ext_vector_type(4)));

#define TM 128
#define TN 128
#define BKK 64

typedef __attribute__((address_space(3))) uint32_t lds_u32;
typedef __attribute__((address_space(1))) uint32_t glb_u32;

// ---------------- GEMM: C = alpha * A @ Bt^T (+bias) (+relu) ----------------
// m97-style: 128x128 tile, BK=64, 4 waves, linear LDS, global_load_lds width-16.
// A: [M,K] bf16 row-major (lda). Bt: [N,K] bf16 row-major (ldb)  (B^T form).
// C row addressing: ro = coff + (row>>msub_shift)*msub_stride + (row&mask)*ldc
// batch z: A += z*sA, Bt += z*sB, bias += z*sBias,
//          coff = (z>>zshift)*sC_hi + (z&((1<<zshift)-1))*sC_lo
template<bool OUT_BF16, bool BIAS, bool RELU, bool CSKIP, bool CKLIM>
__global__ __launch_bounds__(256, 2)
void gemm_bt_kernel(const bf16_t* __restrict__ A,
                    const bf16_t* __restrict__ Bt,
                    const float* __restrict__ bias,
                    void* __restrict__ Cv,
                    int M, int N, int K,
                    int lda, int ldb, int ldc,
                    long long sA, long long sB, long long sBias,
                    int zshift, long long sC_hi, long long sC_lo,
                    int msub_shift, long long msub_stride,
                    float alpha)
{
  const int zb = blockIdx.z;
  const int m0 = blockIdx.x * TM;
  const int n0 = blockIdx.y * TN;
  if (CSKIP && n0 > m0 + TM - 1) return;   // fully-masked causal tile
  int kend = K;
  if (CKLIM) { int ke = m0 + TM; kend = ke < K ? ke : K; }

  const bf16_t* Az = A + (long long)zb * sA;
  const bf16_t* Bz = Bt + (long long)zb * sB;
  const long long coff = ((long long)(zb >> zshift)) * sC_hi
                       + ((long long)(zb & ((1 << zshift) - 1))) * sC_lo;

  __shared__ __align__(16) bf16_t As[TM * BKK];
  __shared__ __align__(16) bf16_t Bs[TN * BKK];

  const int tid = threadIdx.x;
  const int wv = tid >> 6;
  const int lane = tid & 63;
  const int wm = (wv >> 1) * 64;
  const int wn = (wv & 1) * 64;
  const int fr = lane & 15;
  const int fg = lane >> 4;

  f32x4_t acc[4][4];
  #pragma unroll
  for (int i = 0; i < 4; ++i)
    #pragma unroll
    for (int j = 0; j < 4; ++j)
      acc[i][j] = (f32x4_t){0.f, 0.f, 0.f, 0.f};

  // staging: per K-step the A tile is 128x64 bf16 = 16KB = 16 segments of 1KB.
  // wave wv stages segments g = wv*4+s. lane l covers tile element offset l*8:
  //   row = g*8 + l/8, col = (l&7)*8  ->  LDS linear offset g*512 + l*8. (lds dest
  //   of global_load_lds is uniform base + lane*16B, matching exactly.)
  const bf16_t* ga = Az + (long long)(m0 + (wv << 5) + (lane >> 3)) * lda + ((lane & 7) << 3);
  const bf16_t* gb = Bz + (long long)(n0 + (wv << 5) + (lane >> 3)) * ldb + ((lane & 7) << 3);

  for (int k0 = 0; k0 < kend; k0 += BKK) {
    __syncthreads();
    #pragma unroll
    for (int s = 0; s < 4; ++s) {
      __builtin_amdgcn_global_load_lds(
        (const glb_u32*)(ga + (long long)s * 8 * lda + k0),
        (lds_u32*)(As + (wv * 4 + s) * 512), 16, 0, 0);
      __builtin_amdgcn_global_load_lds(
        (const glb_u32*)(gb + (long long)s * 8 * ldb + k0),
        (lds_u32*)(Bs + (wv * 4 + s) * 512), 16, 0, 0);
    }
    __syncthreads();
    #pragma unroll
    for (int kc = 0; kc < 2; ++kc) {
      bf16x8_t af[4], bfr[4];
      #pragma unroll
      for (int i = 0; i < 4; ++i)
        af[i] = *(const bf16x8_t*)&As[(wm + i*16 + fr) * BKK + kc*32 + fg*8];
      #pragma unroll
      for (int j = 0; j < 4; ++j)
        bfr[j] = *(const bf16x8_t*)&Bs[(wn + j*16 + fr) * BKK + kc*32 + fg*8];
      #pragma unroll
      for (int i = 0; i < 4; ++i)
        #pragma unroll
        for (int j = 0; j < 4; ++j)
          acc[i][j] = __builtin_amdgcn_mfma_f32_16x16x32_bf16(af[i], bfr[j], acc[i][j], 0, 0, 0);
    }
  }

  #pragma unroll
  for (int i = 0; i < 4; ++i) {
    #pragma unroll
    for (int e = 0; e < 4; ++e) {
      const int row = m0 + wm + i*16 + fg*4 + e;
      const long long ro = coff
        + ((long long)(row >> msub_shift)) * msub_stride
        + (long long)(row & ((1 << msub_shift) - 1)) * (long long)ldc;
      #pragma unroll
      for (int j = 0; j < 4; ++j) {
        const int col = n0 + wn + j*16 + fr;
        float v = acc[i][j][e] * alpha;
        if (BIAS) v += bias[(long long)zb * sBias + col];
        if (RELU) v = v > 0.f ? v : 0.f;
        if (OUT_BF16) ((bf16_t*)Cv)[ro + col] = (bf16_t)v;
        else          ((float*)Cv)[ro + col]  = v;
      }
    }
  }
}

// ---------------- transpose (+cast to bf16): out[C][R] = in[R][C] ----------------
template<typename TIN>
__global__ void transpose_kernel(const TIN* __restrict__ in, bf16_t* __restrict__ out,
                                 int R, int C, long long sIn, long long sOut)
{
  __shared__ float tile[32][33];
  const long long zi = (long long)blockIdx.z * sIn;
  const long long zo = (long long)blockIdx.z * sOut;
  const int c0 = blockIdx.x * 32, r0 = blockIdx.y * 32;
  const int tx = threadIdx.x, ty = threadIdx.y;  // 32 x 8
  #pragma unroll
  for (int i = 0; i < 4; ++i) {
    int r = r0 + ty + i*8;
    tile[ty + i*8][tx] = (float)in[zi + (long long)r * C + c0 + tx];
  }
  __syncthreads();
  #pragma unroll
  for (int i = 0; i < 4; ++i) {
    int c = c0 + ty + i*8;
    out[zo + (long long)c * R + r0 + tx] = (bf16_t)tile[tx][ty + i*8];
  }
}

// ---------------- q/k/v weight transpose for one layer, z=0..11 ----------------
__global__ void qkvT_kernel(const float* __restrict__ wq, const float* __restrict__ wk,
                            const float* __restrict__ wv, bf16_t* __restrict__ out, int layer)
{
  __shared__ float tile[32][33];
  const int z = blockIdx.z, op = z >> 2, h = z & 3;
  const float* src = (op == 0 ? wq : op == 1 ? wk : wv)
                   + ((long long)layer * NHEAD + h) * HD * HD;
  bf16_t* dst = out + (long long)z * HD * HD;
  const int c0 = blockIdx.x * 32, r0 = blockIdx.y * 32;
  const int tx = threadIdx.x, ty = threadIdx.y;
  #pragma unroll
  for (int i = 0; i < 4; ++i)
    tile[ty + i*8][tx] = src[(long long)(r0 + ty + i*8) * HD + c0 + tx];
  __syncthreads();
  #pragma unroll
  for (int i = 0; i < 4; ++i)
    dst[(long long)(c0 + ty + i*8) * HD + r0 + tx] = (bf16_t)tile[tx][ty + i*8];
}

// ---------------- two-source f32 -> bf16 convert (out laid [a | b]) ----------------
__global__ void convert2_kernel(const float* __restrict__ a, const float* __restrict__ b,
                                bf16_t* __restrict__ out, long long n)
{
  long long i = (long long)blockIdx.x * blockDim.x + threadIdx.x;
  long long stride = (long long)gridDim.x * blockDim.x;
  for (; i < 2*n; i += stride)
    out[i] = (bf16_t)(i < n ? a[i] : b[i - n]);
}

// ---------------- diagnostic fill ----------------
__global__ void fill_kernel(float* __restrict__ out, long long n, float v)
{
  long long i = (long long)blockIdx.x * blockDim.x + threadIdx.x;
  long long stride = (long long)gridDim.x * blockDim.x;
  for (; i < n; i += stride) out[i] = v;
}

// ---------------- positions: pos = cumsum(mask) - 1 ----------------
__global__ void pos_kernel(const int* __restrict__ mask, float* __restrict__ pos)
{
  __shared__ float scn[S_LEN];
  const int b = blockIdx.x, t = threadIdx.x;
  scn[t] = (float)(mask[b * S_LEN + t] != 0);
  __syncthreads();
  for (int off = 1; off < S_LEN; off <<= 1) {
    float add = (t >= off) ? scn[t - off] : 0.f;
    __syncthreads();
    scn[t] += add;
    __syncthreads();
  }
  pos[b * S_LEN + t] = scn[t] - 1.0f;
}

// ---------------- embedding + positional encoding ----------------
__global__ void embed_kernel(const int* __restrict__ ids, const int* __restrict__ mask,
                             const float* __restrict__ pos, const float* __restrict__ emb,
                             float* __restrict__ x, bf16_t* __restrict__ xb)
{
  const int idx = blockIdx.x * 256 + threadIdx.x;
  const int i = idx & 255;
  const int bs = idx >> 8;
  const int id = ids[bs];
  const float m = (float)(mask[bs] != 0);
  const float p = pos[bs];
  const float dv = __expf(-(float)(2 * i) * (9.210340371976184f / (float)HD));
  const float sv = __sinf(p * dv) * m;
  const float e0 = emb[id * HD + 2*i], e1 = emb[id * HD + 2*i + 1];
  const float x0 = e0 + sv, x1 = e1 + sv;
  x[(long long)bs * HD + 2*i]     = x0;
  x[(long long)bs * HD + 2*i + 1] = x1;
  xb[(long long)bs * HD + 2*i]     = (bf16_t)x0;
  xb[(long long)bs * HD + 2*i + 1] = (bf16_t)x1;
}

// ---------------- softmax: one read pass, regs-resident row ----------------
__global__ void softmax_kernel(const float* __restrict__ sc, bf16_t* __restrict__ P,
                               const int* __restrict__ mask, int pair0)
{
  const int s = blockIdx.x;
  const int pz = blockIdx.y;
  const int b = (pair0 + pz) >> 2;
  const float* src = sc + ((long long)pz * S_LEN + s) * S_LEN;
  bf16_t* dst = P + ((long long)pz * S_LEN + s) * S_LEN;
  const bool qvalid = mask[b * S_LEN + s] != 0;
  const int tid = threadIdx.x;
  __shared__ float red[4];

  float v[4]; bool ok[4];
  #pragma unroll
  for (int j = 0; j < 4; ++j) {
    const int t = tid + j*256;
    ok[j] = (t <= s) && (mask[b * S_LEN + t] != 0);
    v[j] = ok[j] ? src[t] : -INFINITY;
  }
  float mx = fmaxf(fmaxf(v[0], v[1]), fmaxf(v[2], v[3]));
  #pragma unroll
  for (int o = 32; o; o >>= 1) mx = fmaxf(mx, __shfl_xor(mx, o));
  if ((tid & 63) == 0) red[tid >> 6] = mx;
  __syncthreads();
  mx = fmaxf(fmaxf(red[0], red[1]), fmaxf(red[2], red[3]));
  __syncthreads();

  float e[4];
  float sum = 0.f;
  #pragma unroll
  for (int j = 0; j < 4; ++j) {
    e[j] = ok[j] ? __expf(v[j] - mx) : 0.f;
    sum += e[j];
  }
  #pragma unroll
  for (int o = 32; o; o >>= 1) sum += __shfl_xor(sum, o);
  if ((tid & 63) == 0) red[tid >> 6] = sum;
  __syncthreads();
  sum = red[0] + red[1] + red[2] + red[3];

  const float inv = (qvalid && sum > 0.f) ? 1.f / sum : 0.f;
  #pragma unroll
  for (int j = 0; j < 4; ++j)
    dst[tid + j*256] = (bf16_t)(e[j] * inv);
}

// ---------------- layernorm: x = LN(x + t1 + t2 + bias); emit bf16 copy ----------------
__global__ void ln_kernel(float* __restrict__ x, const float* __restrict__ t1,
                          const float* __restrict__ t2, const float* __restrict__ bias,
                          const float* __restrict__ g, const float* __restrict__ b,
                          bf16_t* __restrict__ xb)
{
  __shared__ float red[4];
  const long long row = blockIdx.x;
  const int tid = threadIdx.x;  // 256, 2 elems each
  float v0 = x[row * HD + tid]       + t1[row * HD + tid]       + t2[row * HD + tid]       + bias[tid];
  float v1 = x[row * HD + tid + 256] + t1[row * HD + tid + 256] + t2[row * HD + tid + 256] + bias[tid + 256];
  float s = v0 + v1;
  #pragma unroll
  for (int o = 32; o; o >>= 1) s += __shfl_xor(s, o);
  if ((tid & 63) == 0) red[tid >> 6] = s;
  __syncthreads();
  const float mu = (red[0] + red[1] + red[2] + red[3]) * (1.f / (float)HD);
  __syncthreads();
  const float d0 = v0 - mu, d1 = v1 - mu;
  float q = d0 * d0 + d1 * d1;
  #pragma unroll
  for (int o = 32; o; o >>= 1) q += __shfl_xor(q, o);
  if ((tid & 63) == 0) red[tid >> 6] = q;
  __syncthreads();
  const float var = (red[0] + red[1] + red[2] + red[3]) * (1.f / (float)HD);
  const float inv = rsqrtf(var + 1e-5f);
  const float y0 = d0 * inv * g[tid]       + b[tid];
  const float y1 = d1 * inv * g[tid + 256] + b[tid + 256];
  x[row * HD + tid]       = y0;
  x[row * HD + tid + 256] = y1;
  xb[row * HD + tid]       = (bf16_t)y0;
  xb[row * HD + tid + 256] = (bf16_t)y1;
}

extern "C" void kernel_launch(void* const* d_in, const int* in_sizes, int n_in,
                              void* d_out, int out_size, void* d_ws, size_t ws_size,
                              hipStream_t stream)
{
  (void)in_sizes; (void)n_in;
  const int*   ids   = (const int*)d_in[0];
  const int*   amask = (const int*)d_in[1];
  const float* emb   = (const float*)d_in[2];
  const float* wq    = (const float*)d_in[3];
  const float* wk    = (const float*)d_in[4];
  const float* wv    = (const float*)d_in[5];
  const float* wo_w  = (const float*)d_in[6];
  const float* wo_b  = (const float*)d_in[7];
  const float* ln1_g = (const float*)d_in[8];
  const float* ln1_b = (const float*)d_in[9];
  const float* ff1_w = (const float*)d_in[10];
  const float* ff1_b = (const float*)d_in[11];
  const float* ff2_w = (const float*)d_in[12];
  const float* ff2_b = (const float*)d_in[13];
  const float* ln2_g = (const float*)d_in[14];
  const float* ln2_b = (const float*)d_in[15];
  const float* lm_w  = (const float*)d_in[16];

  const long long MROW = (long long)BATCH * S_LEN;   // 8192
  const size_t MBc = 1ull << 20;
  char* p = (char*)d_ws;
  auto alloc = [&](size_t bytes) { char* r = p; p += (bytes + 255) & ~(size_t)255; return r; };

  // persistent (~68 MB)
  float*  x     = (float*) alloc(MROW * HD * 4);                // 16 MB
  bf16_t* xb    = (bf16_t*)alloc(MROW * HD * 2);                // 8 MB
  bf16_t* ob    = (bf16_t*)alloc(MROW * (NHEAD*HD) * 2);        // 32 MB
  bf16_t* wqkvT = (bf16_t*)alloc(12LL * HD * HD * 2);           // 6 MB
  bf16_t* woT   = (bf16_t*)alloc((long long)HD * FFD * 2);      // 2 MB
  bf16_t* wff1  = (bf16_t*)alloc((long long)FFD * HD * 2);      // 2 MB
  bf16_t* wff2  = (bf16_t*)alloc((long long)HD * FFD * 2);      // 2 MB
  bf16_t* lmT   = (bf16_t*)alloc((long long)NTOK * HD * 2);
  float*  pos   = (float*) alloc(MROW * 4);

  const size_t used = (size_t)(p - (char*)d_ws);
  const size_t rem  = ws_size > used ? ws_size - used : 0;

  // region A needs: attention chunk = P*(q1+k1+v1+vT1 + sc4 + P2) MB; FF phase = 64 MB
  int P = 0;
  if      (rem >= 80 * MBc) P = 8;
  else if (rem >= 64 * MBc) P = 4;
  if (P == 0) {
    fill_kernel<<<1024, 256, 0, stream>>>((float*)d_out, (long long)out_size,
                                          (float)(ws_size >> 20));
    return;
  }

  char* A = p;
  const long long pairE = (long long)S_LEN * HD;
  bf16_t* qc  = (bf16_t*)A;
  bf16_t* kc  = qc  + (long long)P * pairE;
  bf16_t* vc  = kc  + (long long)P * pairE;
  bf16_t* vTc = vc  + (long long)P * pairE;
  float*  scb = (float*)(vTc + (long long)P * pairE);
  bf16_t* Pb  = (bf16_t*)(scb + (long long)P * S_LEN * S_LEN);
  float*  tmp  = (float*)A;                       // FF phase aliases
  float*  tmp2 = tmp + MROW * HD;
  bf16_t* ffb  = (bf16_t*)(A + 32 * MBc);

  const dim3 tb(32, 8);
  transpose_kernel<float><<<dim3(4,16,1), tb, 0, stream>>>(lm_w, lmT, HD, NTOK, 0, 0);
  pos_kernel<<<BATCH, S_LEN, 0, stream>>>(amask, pos);
  embed_kernel<<<8192, 256, 0, stream>>>(ids, amask, pos, emb, x, xb);

  const int nch = 32 / P;
  const int bpc = P / NHEAD;

  for (int l = 0; l < NBLK; ++l) {
    // per-layer weight prep
    qkvT_kernel<<<dim3(16,16,12), tb, 0, stream>>>(wq, wk, wv, wqkvT, l);
    transpose_kernel<float><<<dim3(16,64,1), tb, 0, stream>>>(
      wo_w + (long long)l*FFD*HD, woT, FFD, HD, 0, 0);
    convert2_kernel<<<2048, 256, 0, stream>>>(
      ff1_w + (long long)l*FFD*HD, ff2_w + (long long)l*HD*FFD, wff1, (long long)FFD*HD);

    for (int c = 0; c < nch; ++c) {
      const int b0 = c * bpc;
      const int pair0 = b0 * NHEAD;
      const int Mch = bpc * S_LEN;

      // fused q/k/v projections: z = op*4 + head (12 batches, 768 blocks at P=8)
      gemm_bt_kernel<true,false,false,false,false><<<dim3(Mch/TM,4,12),256,0,stream>>>(
        xb + (long long)b0*S_LEN*HD, wqkvT, nullptr, qc, Mch, HD, HD, HD, HD, HD,
        0, (long long)HD*HD, 0,
        2, (long long)P*pairE, (long long)S_LEN*HD,
        10, (long long)NHEAD*S_LEN*HD, 1.f);

      transpose_kernel<bf16_t><<<dim3(16,32,P), tb, 0, stream>>>(
        vc, vTc, S_LEN, HD, (long long)S_LEN*HD, (long long)HD*S_LEN);

      // scores = q @ k^T / sqrt(512)   (causal tile skip)
      gemm_bt_kernel<false,false,false,true,false><<<dim3(8,8,P),256,0,stream>>>(
        qc, kc, nullptr, scb,
        S_LEN, S_LEN, HD, HD, HD, S_LEN,
        (long long)S_LEN*HD, (long long)S_LEN*HD, 0,
        30, 0, (long long)S_LEN*S_LEN,
        30, 0, 0.044194173824159216f);
      softmax_kernel<<<dim3(S_LEN,P),256,0,stream>>>(scb, Pb, amask, pair0);
      // o = P @ v   (causal k-limit)
      gemm_bt_kernel<true,false,false,false,true><<<dim3(8,4,P),256,0,stream>>>(
        Pb, vTc, nullptr,
        ob + (long long)b0*S_LEN*(NHEAD*HD),
        S_LEN, HD, S_LEN, S_LEN, S_LEN, NHEAD*HD,
        (long long)S_LEN*S_LEN, (long long)HD*S_LEN, 0,
        2, (long long)S_LEN*NHEAD*HD, HD,
        30, 0, 1.f);
    }

    // mh = o @ wo (split-K=2 -> tmp, tmp2; bias folded into LN)
    gemm_bt_kernel<false,false,false,false,false><<<dim3(64,4,2),256,0,stream>>>(
      ob, woT, nullptr, tmp,
      (int)MROW, HD, 1024, NHEAD*HD, NHEAD*HD, HD,
      1024, 1024, 0,
      0, (long long)MROW*HD, 0,
      30, 0, 1.f);
    ln_kernel<<<8192,256,0,stream>>>(x, tmp, tmp2, wo_b + l*HD, ln1_g + l*HD, ln1_b + l*HD, xb);

    // ff1: relu(xb @ ff1^T + b1) -> ffb (bf16)
    gemm_bt_kernel<true,true,true,false,false><<<dim3(64,16,1),256,0,stream>>>(
      xb, wff1, ff1_b + l*FFD, ffb,
      (int)MROW, FFD, HD, HD, HD, FFD,
      0, 0, 0, 30, 0, 0, 30, 0, 1.f);
    // ff2 (split-K=2 -> tmp, tmp2; bias folded into LN)
    gemm_bt_kernel<false,false,false,false,false><<<dim3(64,4,2),256,0,stream>>>(
      ffb, wff2, nullptr, tmp,
      (int)MROW, HD, 1024, FFD, FFD, HD,
      1024, 1024, 0,
      0, (long long)MROW*HD, 0,
      30, 0, 1.f);
    ln_kernel<<<8192,256,0,stream>>>(x, tmp, tmp2, ff2_b + l*HD, ln2_g + l*HD, ln2_b + l*HD, xb);
  }

  // lm head -> d_out (f32)
  gemm_bt_kernel<false,false,false,false,false><<<dim3(64,1,1),256,0,stream>>>(
    xb, lmT, nullptr, (float*)d_out,
    (int)MROW, NTOK, HD, HD, HD, NTOK,
    0, 0, 0, 30, 0, 0, 30, 0, 1.f);
}

// Round 4
// 1161.559 us; speedup vs baseline: 1.7826x; 1.1589x over previous
//
#include <hip/hip_runtime.h>
#include <hip/hip_bf16.h>

#define S_LEN 1024
#define BATCH 8
#define HD 512
#define FFD 2048
#define NHEAD 4
#define NBLK 3
#define NTOK 128

typedef __bf16 bf16_t;
typedef __bf16 bf16x4_t __attribute__((ext_vector_type(4)));
typedef __bf16 bf16x8_t __attribute__((ext_vector_type(8)));
typedef float f32x4_t __attribute__((ext_vector_type(4)));

#define TM 128
#define TN 128
#define BKK 64

typedef __attribute__((address_space(3))) uint32_t lds_u32;
typedef __attribute__((address_space(1))) uint32_t glb_u32;

// ---------------- GEMM: C = alpha * A @ Bt^T (+bias) (+relu) ----------------
// 128x128 tile, BK=64, 4 waves, global_load_lds width-16, DOUBLE-BUFFERED LDS
// with next-tile prefetch, XOR-swizzled LDS layout (conflict-free ds_read_b128).
// A: [M,K] bf16 row-major (lda). Bt: [N,K] bf16 row-major (ldb)  (B^T form).
// C row addressing: ro = coff + (row>>msub_shift)*msub_stride + (row&mask)*ldc
// batch z: A += z*sA, Bt += z*sB, bias += z*sBias,
//          coff = (z>>zshift)*sC_hi + (z&((1<<zshift)-1))*sC_lo
template<bool OUT_BF16, bool BIAS, bool RELU, bool CSKIP, bool CKLIM>
__global__ __launch_bounds__(256, 2)
void gemm_bt_kernel(const bf16_t* __restrict__ A,
                    const bf16_t* __restrict__ Bt,
                    const float* __restrict__ bias,
                    void* __restrict__ Cv,
                    int M, int N, int K,
                    int lda, int ldb, int ldc,
                    long long sA, long long sB, long long sBias,
                    int zshift, long long sC_hi, long long sC_lo,
                    int msub_shift, long long msub_stride,
                    float alpha)
{
  const int zb = blockIdx.z;
  const int m0 = blockIdx.x * TM;
  const int n0 = blockIdx.y * TN;
  if (CSKIP && n0 > m0 + TM - 1) return;   // fully-masked causal tile
  int kend = K;
  if (CKLIM) { int ke = m0 + TM; kend = ke < K ? ke : K; }

  const bf16_t* Az = A + (long long)zb * sA;
  const bf16_t* Bz = Bt + (long long)zb * sB;
  const long long coff = ((long long)(zb >> zshift)) * sC_hi
                       + ((long long)(zb & ((1 << zshift) - 1))) * sC_lo;

  __shared__ __align__(16) bf16_t As[2][TM * BKK];
  __shared__ __align__(16) bf16_t Bs[2][TN * BKK];

  const int tid = threadIdx.x;
  const int wv = tid >> 6;
  const int lane = tid & 63;
  const int wm = (wv >> 1) * 64;
  const int wn = (wv & 1) * 64;
  const int fr = lane & 15;
  const int fg = lane >> 4;
  const int sw = fr & 7;              // read-side swizzle key

  f32x4_t acc[4][4];
  #pragma unroll
  for (int i = 0; i < 4; ++i)
    #pragma unroll
    for (int j = 0; j < 4; ++j)
      acc[i][j] = (f32x4_t){0.f, 0.f, 0.f, 0.f};

  // staging: tile 128x64 bf16 = 16 segs of 1KB; wave wv stages segs wv*4+s.
  // lane l -> row (l>>3), SWIZZLED col ((l&7)^(l>>3))*8, LDS dest linear l*16B.
  // => LDS(r, c) holds global col ((c/8) ^ (r&7))*8; read col ((kc*4+fg)^(fr&7))*8.
  const bf16_t* ga = Az + (long long)(m0 + (wv << 5) + (lane >> 3)) * lda
                   + (((lane & 7) ^ (lane >> 3)) << 3);
  const bf16_t* gb = Bz + (long long)(n0 + (wv << 5) + (lane >> 3)) * ldb
                   + (((lane & 7) ^ (lane >> 3)) << 3);

  auto stage = [&](int buf, int k0) {
    #pragma unroll
    for (int s = 0; s < 4; ++s) {
      __builtin_amdgcn_global_load_lds(
        (const glb_u32*)(ga + (long long)s * 8 * lda + k0),
        (lds_u32*)(&As[buf][(wv * 4 + s) * 512]), 16, 0, 0);
      __builtin_amdgcn_global_load_lds(
        (const glb_u32*)(gb + (long long)s * 8 * ldb + k0),
        (lds_u32*)(&Bs[buf][(wv * 4 + s) * 512]), 16, 0, 0);
    }
  };

  const int nt = kend >> 6;
  stage(0, 0);
  __syncthreads();
  int cur = 0;
  for (int t = 0; t < nt; ++t) {
    if (t + 1 < nt) stage(cur ^ 1, (t + 1) << 6);   // prefetch flies under compute
    #pragma unroll
    for (int kc = 0; kc < 2; ++kc) {
      const int ca = ((kc * 4 + fg) ^ sw) << 3;
      bf16x8_t af[4], bfr[4];
      #pragma unroll
      for (int i = 0; i < 4; ++i)
        af[i] = *(const bf16x8_t*)&As[cur][(wm + i*16 + fr) * BKK + ca];
      #pragma unroll
      for (int j = 0; j < 4; ++j)
        bfr[j] = *(const bf16x8_t*)&Bs[cur][(wn + j*16 + fr) * BKK + ca];
      #pragma unroll
      for (int i = 0; i < 4; ++i)
        #pragma unroll
        for (int j = 0; j < 4; ++j)
          acc[i][j] = __builtin_amdgcn_mfma_f32_16x16x32_bf16(af[i], bfr[j], acc[i][j], 0, 0, 0);
    }
    __syncthreads();   // drains vmcnt: prefetch had the whole compute to land
    cur ^= 1;
  }

  #pragma unroll
  for (int i = 0; i < 4; ++i) {
    #pragma unroll
    for (int e = 0; e < 4; ++e) {
      const int row = m0 + wm + i*16 + fg*4 + e;
      const long long ro = coff
        + ((long long)(row >> msub_shift)) * msub_stride
        + (long long)(row & ((1 << msub_shift) - 1)) * (long long)ldc;
      #pragma unroll
      for (int j = 0; j < 4; ++j) {
        const int col = n0 + wn + j*16 + fr;
        float v = acc[i][j][e] * alpha;
        if (BIAS) v += bias[(long long)zb * sBias + col];
        if (RELU) v = v > 0.f ? v : 0.f;
        if (OUT_BF16) ((bf16_t*)Cv)[ro + col] = (bf16_t)v;
        else          ((float*)Cv)[ro + col]  = v;
      }
    }
  }
}

// ---------------- transpose (+cast to bf16): out[C][R] = in[R][C] ----------------
template<typename TIN>
__global__ void transpose_kernel(const TIN* __restrict__ in, bf16_t* __restrict__ out,
                                 int R, int C, long long sIn, long long sOut)
{
  __shared__ float tile[32][33];
  const long long zi = (long long)blockIdx.z * sIn;
  const long long zo = (long long)blockIdx.z * sOut;
  const int c0 = blockIdx.x * 32, r0 = blockIdx.y * 32;
  const int tx = threadIdx.x, ty = threadIdx.y;  // 32 x 8
  #pragma unroll
  for (int i = 0; i < 4; ++i) {
    int r = r0 + ty + i*8;
    tile[ty + i*8][tx] = (float)in[zi + (long long)r * C + c0 + tx];
  }
  __syncthreads();
  #pragma unroll
  for (int i = 0; i < 4; ++i) {
    int c = c0 + ty + i*8;
    out[zo + (long long)c * R + r0 + tx] = (bf16_t)tile[tx][ty + i*8];
  }
}

// ---------------- q/k/v weight transpose for one layer, z=0..11 ----------------
__global__ void qkvT_kernel(const float* __restrict__ wq, const float* __restrict__ wk,
                            const float* __restrict__ wv, bf16_t* __restrict__ out, int layer)
{
  __shared__ float tile[32][33];
  const int z = blockIdx.z, op = z >> 2, h = z & 3;
  const float* src = (op == 0 ? wq : op == 1 ? wk : wv)
                   + ((long long)layer * NHEAD + h) * HD * HD;
  bf16_t* dst = out + (long long)z * HD * HD;
  const int c0 = blockIdx.x * 32, r0 = blockIdx.y * 32;
  const int tx = threadIdx.x, ty = threadIdx.y;
  #pragma unroll
  for (int i = 0; i < 4; ++i)
    tile[ty + i*8][tx] = src[(long long)(r0 + ty + i*8) * HD + c0 + tx];
  __syncthreads();
  #pragma unroll
  for (int i = 0; i < 4; ++i)
    dst[(long long)(c0 + ty + i*8) * HD + r0 + tx] = (bf16_t)tile[tx][ty + i*8];
}

// ---------------- two-source f32 -> bf16 convert (out laid [a | b]) ----------------
__global__ void convert2_kernel(const float* __restrict__ a, const float* __restrict__ b,
                                bf16_t* __restrict__ out, long long n)
{
  long long i = (long long)blockIdx.x * blockDim.x + threadIdx.x;
  long long stride = (long long)gridDim.x * blockDim.x;
  for (; i < 2*n; i += stride)
    out[i] = (bf16_t)(i < n ? a[i] : b[i - n]);
}

// ---------------- diagnostic fill ----------------
__global__ void fill_kernel(float* __restrict__ out, long long n, float v)
{
  long long i = (long long)blockIdx.x * blockDim.x + threadIdx.x;
  long long stride = (long long)gridDim.x * blockDim.x;
  for (; i < n; i += stride) out[i] = v;
}

// ---------------- positions: pos = cumsum(mask) - 1 ----------------
__global__ void pos_kernel(const int* __restrict__ mask, float* __restrict__ pos)
{
  __shared__ float scn[S_LEN];
  const int b = blockIdx.x, t = threadIdx.x;
  scn[t] = (float)(mask[b * S_LEN + t] != 0);
  __syncthreads();
  for (int off = 1; off < S_LEN; off <<= 1) {
    float add = (t >= off) ? scn[t - off] : 0.f;
    __syncthreads();
    scn[t] += add;
    __syncthreads();
  }
  pos[b * S_LEN + t] = scn[t] - 1.0f;
}

// ---------------- embedding + positional encoding ----------------
__global__ void embed_kernel(const int* __restrict__ ids, const int* __restrict__ mask,
                             const float* __restrict__ pos, const float* __restrict__ emb,
                             float* __restrict__ x, bf16_t* __restrict__ xb)
{
  const int idx = blockIdx.x * 256 + threadIdx.x;
  const int i = idx & 255;
  const int bs = idx >> 8;
  const int id = ids[bs];
  const float m = (float)(mask[bs] != 0);
  const float p = pos[bs];
  const float dv = __expf(-(float)(2 * i) * (9.210340371976184f / (float)HD));
  const float sv = __sinf(p * dv) * m;
  const float e0 = emb[id * HD + 2*i], e1 = emb[id * HD + 2*i + 1];
  const float x0 = e0 + sv, x1 = e1 + sv;
  x[(long long)bs * HD + 2*i]     = x0;
  x[(long long)bs * HD + 2*i + 1] = x1;
  xb[(long long)bs * HD + 2*i]     = (bf16_t)x0;
  xb[(long long)bs * HD + 2*i + 1] = (bf16_t)x1;
}

// ---------------- softmax, bf16 scores in-place -> bf16 P ----------------
__global__ void softmax_kernel(bf16_t* __restrict__ scP,
                               const int* __restrict__ mask, int pair0)
{
  const int s = blockIdx.x;
  const int pz = blockIdx.y;
  const int b = (pair0 + pz) >> 2;
  bf16_t* row = scP + ((long long)pz * S_LEN + s) * S_LEN;
  const bool qvalid = mask[b * S_LEN + s] != 0;
  const int tid = threadIdx.x;
  const int t0 = tid * 4;
  __shared__ float red[4];

  bf16x4_t raw = *(const bf16x4_t*)&row[t0];
  float v[4]; bool ok[4];
  #pragma unroll
  for (int j = 0; j < 4; ++j) {
    const int t = t0 + j;
    ok[j] = (t <= s) && (mask[b * S_LEN + t] != 0);
    v[j] = ok[j] ? (float)raw[j] : -INFINITY;
  }
  float mx = fmaxf(fmaxf(v[0], v[1]), fmaxf(v[2], v[3]));
  #pragma unroll
  for (int o = 32; o; o >>= 1) mx = fmaxf(mx, __shfl_xor(mx, o));
  if ((tid & 63) == 0) red[tid >> 6] = mx;
  __syncthreads();
  mx = fmaxf(fmaxf(red[0], red[1]), fmaxf(red[2], red[3]));
  __syncthreads();

  float e[4];
  float sum = 0.f;
  #pragma unroll
  for (int j = 0; j < 4; ++j) {
    e[j] = ok[j] ? __expf(v[j] - mx) : 0.f;
    sum += e[j];
  }
  #pragma unroll
  for (int o = 32; o; o >>= 1) sum += __shfl_xor(sum, o);
  if ((tid & 63) == 0) red[tid >> 6] = sum;
  __syncthreads();
  sum = red[0] + red[1] + red[2] + red[3];

  const float inv = (qvalid && sum > 0.f) ? 1.f / sum : 0.f;
  bf16x4_t o4;
  #pragma unroll
  for (int j = 0; j < 4; ++j) o4[j] = (bf16_t)(e[j] * inv);
  *(bf16x4_t*)&row[t0] = o4;
}

// ---------------- layernorm: x = LN(x + sum_i tparts[i] + bias); emit bf16 ----------------
__global__ void ln_kernel(float* __restrict__ x, const float* __restrict__ tparts,
                          int ns, long long pstride,
                          const float* __restrict__ bias,
                          const float* __restrict__ g, const float* __restrict__ b,
                          bf16_t* __restrict__ xb)
{
  __shared__ float red[4];
  const long long row = blockIdx.x;
  const int tid = threadIdx.x;  // 256, 2 elems each
  float v0 = x[row * HD + tid]       + bias[tid];
  float v1 = x[row * HD + tid + 256] + bias[tid + 256];
  for (int i = 0; i < ns; ++i) {
    v0 += tparts[i * pstride + row * HD + tid];
    v1 += tparts[i * pstride + row * HD + tid + 256];
  }
  float s = v0 + v1;
  #pragma unroll
  for (int o = 32; o; o >>= 1) s += __shfl_xor(s, o);
  if ((tid & 63) == 0) red[tid >> 6] = s;
  __syncthreads();
  const float mu = (red[0] + red[1] + red[2] + red[3]) * (1.f / (float)HD);
  __syncthreads();
  const float d0 = v0 - mu, d1 = v1 - mu;
  float q = d0 * d0 + d1 * d1;
  #pragma unroll
  for (int o = 32; o; o >>= 1) q += __shfl_xor(q, o);
  if ((tid & 63) == 0) red[tid >> 6] = q;
  __syncthreads();
  const float var = (red[0] + red[1] + red[2] + red[3]) * (1.f / (float)HD);
  const float inv = rsqrtf(var + 1e-5f);
  const float y0 = d0 * inv * g[tid]       + b[tid];
  const float y1 = d1 * inv * g[tid + 256] + b[tid + 256];
  x[row * HD + tid]       = y0;
  x[row * HD + tid + 256] = y1;
  xb[row * HD + tid]       = (bf16_t)y0;
  xb[row * HD + tid + 256] = (bf16_t)y1;
}

extern "C" void kernel_launch(void* const* d_in, const int* in_sizes, int n_in,
                              void* d_out, int out_size, void* d_ws, size_t ws_size,
                              hipStream_t stream)
{
  (void)in_sizes; (void)n_in;
  const int*   ids   = (const int*)d_in[0];
  const int*   amask = (const int*)d_in[1];
  const float* emb   = (const float*)d_in[2];
  const float* wq    = (const float*)d_in[3];
  const float* wk    = (const float*)d_in[4];
  const float* wv    = (const float*)d_in[5];
  const float* wo_w  = (const float*)d_in[6];
  const float* wo_b  = (const float*)d_in[7];
  const float* ln1_g = (const float*)d_in[8];
  const float* ln1_b = (const float*)d_in[9];
  const float* ff1_w = (const float*)d_in[10];
  const float* ff1_b = (const float*)d_in[11];
  const float* ff2_w = (const float*)d_in[12];
  const float* ff2_b = (const float*)d_in[13];
  const float* ln2_g = (const float*)d_in[14];
  const float* ln2_b = (const float*)d_in[15];
  const float* lm_w  = (const float*)d_in[16];

  const long long MROW = (long long)BATCH * S_LEN;   // 8192
  const size_t MBc = 1ull << 20;
  char* p = (char*)d_ws;
  auto alloc = [&](size_t bytes) { char* r = p; p += (bytes + 255) & ~(size_t)255; return r; };

  // persistent (~68 MB)
  float*  x     = (float*) alloc(MROW * HD * 4);                // 16 MB
  bf16_t* xb    = (bf16_t*)alloc(MROW * HD * 2);                // 8 MB
  bf16_t* ob    = (bf16_t*)alloc(MROW * (NHEAD*HD) * 2);        // 32 MB
  bf16_t* wqkvT = (bf16_t*)alloc(12LL * HD * HD * 2);           // 6 MB
  bf16_t* woT   = (bf16_t*)alloc((long long)HD * FFD * 2);      // 2 MB
  bf16_t* wff1  = (bf16_t*)alloc((long long)FFD * HD * 2);      // 2 MB
  bf16_t* wff2  = (bf16_t*)alloc((long long)HD * FFD * 2);      // 2 MB
  bf16_t* lmT   = (bf16_t*)alloc((long long)NTOK * HD * 2);
  float*  pos   = (float*) alloc(MROW * 4);

  const size_t used = (size_t)(p - (char*)d_ws);
  const size_t rem  = ws_size > used ? ws_size - used : 0;

  // tiers: attn region P*(3+1)MB + P*2MB (bf16 scores);  FF region SK*16+32 MB
  int P = 0, SK = 2;
  if      (rem >= 96 * MBc) { P = 16; SK = 4; }   // attn 96 MB, FF 96 MB
  else if (rem >= 64 * MBc) { P = 8;  SK = 2; }   // attn 48 MB, FF 64 MB
  if (P == 0) {
    fill_kernel<<<1024, 256, 0, stream>>>((float*)d_out, (long long)out_size,
                                          (float)(ws_size >> 20));
    return;
  }

  char* A = p;
  const long long pairE = (long long)S_LEN * HD;
  bf16_t* qc  = (bf16_t*)A;
  bf16_t* kc  = qc  + (long long)P * pairE;
  bf16_t* vc  = kc  + (long long)P * pairE;
  bf16_t* vTc = vc  + (long long)P * pairE;
  bf16_t* scb = vTc + (long long)P * pairE;        // bf16 scores, softmax in-place
  float*  tmp = (float*)A;                          // FF phase aliases (SK partials)
  bf16_t* ffb = (bf16_t*)(A + (size_t)SK * 16 * MBc);

  const dim3 tb(32, 8);
  transpose_kernel<float><<<dim3(4,16,1), tb, 0, stream>>>(lm_w, lmT, HD, NTOK, 0, 0);
  pos_kernel<<<BATCH, S_LEN, 0, stream>>>(amask, pos);
  embed_kernel<<<8192, 256, 0, stream>>>(ids, amask, pos, emb, x, xb);

  const int nch = 32 / P;
  const int bpc = P / NHEAD;

  for (int l = 0; l < NBLK; ++l) {
    qkvT_kernel<<<dim3(16,16,12), tb, 0, stream>>>(wq, wk, wv, wqkvT, l);
    transpose_kernel<float><<<dim3(16,64,1), tb, 0, stream>>>(
      wo_w + (long long)l*FFD*HD, woT, FFD, HD, 0, 0);
    convert2_kernel<<<2048, 256, 0, stream>>>(
      ff1_w + (long long)l*FFD*HD, ff2_w + (long long)l*HD*FFD, wff1, (long long)FFD*HD);

    for (int c = 0; c < nch; ++c) {
      const int b0 = c * bpc;
      const int pair0 = b0 * NHEAD;
      const int Mch = bpc * S_LEN;

      // fused q/k/v projections: z = op*4 + head
      gemm_bt_kernel<true,false,false,false,false><<<dim3(Mch/TM,4,12),256,0,stream>>>(
        xb + (long long)b0*S_LEN*HD, wqkvT, nullptr, qc, Mch, HD, HD, HD, HD, HD,
        0, (long long)HD*HD, 0,
        2, (long long)P*pairE, (long long)S_LEN*HD,
        10, (long long)NHEAD*S_LEN*HD, 1.f);

      transpose_kernel<bf16_t><<<dim3(16,32,P), tb, 0, stream>>>(
        vc, vTc, S_LEN, HD, (long long)S_LEN*HD, (long long)HD*S_LEN);

      // scores = q @ k^T / sqrt(512) -> bf16 scb (causal tile skip)
      gemm_bt_kernel<true,false,false,true,false><<<dim3(8,8,P),256,0,stream>>>(
        qc, kc, nullptr, scb,
        S_LEN, S_LEN, HD, HD, HD, S_LEN,
        (long long)S_LEN*HD, (long long)S_LEN*HD, 0,
        30, 0, (long long)S_LEN*S_LEN,
        30, 0, 0.044194173824159216f);
      softmax_kernel<<<dim3(S_LEN,P),256,0,stream>>>(scb, amask, pair0);
      // o = P @ v   (causal k-limit)
      gemm_bt_kernel<true,false,false,false,true><<<dim3(8,4,P),256,0,stream>>>(
        scb, vTc, nullptr,
        ob + (long long)b0*S_LEN*(NHEAD*HD),
        S_LEN, HD, S_LEN, S_LEN, S_LEN, NHEAD*HD,
        (long long)S_LEN*S_LEN, (long long)HD*S_LEN, 0,
        2, (long long)S_LEN*NHEAD*HD, HD,
        30, 0, 1.f);
    }

    // mh = o @ wo (split-K=SK -> tmp partials; bias folded into LN)
    gemm_bt_kernel<false,false,false,false,false><<<dim3(64,4,SK),256,0,stream>>>(
      ob, woT, nullptr, tmp,
      (int)MROW, HD, (NHEAD*HD)/SK, NHEAD*HD, NHEAD*HD, HD,
      (NHEAD*HD)/SK, (NHEAD*HD)/SK, 0,
      0, (long long)MROW*HD, 0,
      30, 0, 1.f);
    ln_kernel<<<8192,256,0,stream>>>(x, tmp, SK, (long long)MROW*HD,
                                     wo_b + l*HD, ln1_g + l*HD, ln1_b + l*HD, xb);

    // ff1: relu(xb @ ff1^T + b1) -> ffb (bf16)
    gemm_bt_kernel<true,true,true,false,false><<<dim3(64,16,1),256,0,stream>>>(
      xb, wff1, ff1_b + l*FFD, ffb,
      (int)MROW, FFD, HD, HD, HD, FFD,
      0, 0, 0, 30, 0, 0, 30, 0, 1.f);
    // ff2 (split-K=SK)
    gemm_bt_kernel<false,false,false,false,false><<<dim3(64,4,SK),256,0,stream>>>(
      ffb, wff2, nullptr, tmp,
      (int)MROW, HD, FFD/SK, FFD, FFD, HD,
      FFD/SK, FFD/SK, 0,
      0, (long long)MROW*HD, 0,
      30, 0, 1.f);
    ln_kernel<<<8192,256,0,stream>>>(x, tmp, SK, (long long)MROW*HD,
                                     ff2_b + l*HD, ln2_g + l*HD, ln2_b + l*HD, xb);
  }

  // lm head -> d_out (f32)
  gemm_bt_kernel<false,false,false,false,false><<<dim3(64,1,1),256,0,stream>>>(
    xb, lmT, nullptr, (float*)d_out,
    (int)MROW, NTOK, HD, HD, HD, NTOK,
    0, 0, 0, 30, 0, 0, 30, 0, 1.f);
}

// Round 5
// 1007.090 us; speedup vs baseline: 2.0561x; 1.1534x over previous
//
#include <hip/hip_runtime.h>
#include <hip/hip_bf16.h>

#define S_LEN 1024
#define BATCH 8
#define HD 512
#define FFD 2048
#define NHEAD 4
#define NBLK 3
#define NTOK 128

typedef __bf16 bf16_t;
typedef __bf16 bf16x4_t __attribute__((ext_vector_type(4)));
typedef __bf16 bf16x8_t __attribute__((ext_vector_type(8)));
typedef float f32x4_t __attribute__((ext_vector_type(4)));

#define TM 128
#define TN 128
#define BKK 64

typedef __attribute__((address_space(3))) uint32_t lds_u32;
typedef __attribute__((address_space(1))) uint32_t glb_u32;

// ---------------- GEMM: C = alpha * A @ Bt^T (+bias) (+relu) ----------------
// m97 structure: 128x128 tile, BK=64, 4 waves, SINGLE-buffered 32KB LDS,
// global_load_lds width-16, XOR-swizzled LDS (0 bank conflicts), 2-barrier loop.
// Occupancy ~4 blocks/CU provides the latency-hiding TLP (m99/m132 lesson:
// double-buffering halves occupancy and regresses).
// A: [M,K] bf16 row-major (lda). Bt: [N,K] bf16 row-major (ldb)  (B^T form).
// C row addressing: ro = coff + (row>>msub_shift)*msub_stride + (row&mask)*ldc
// batch z: A += z*sA, Bt += z*sB, bias += z*sBias,
//          coff = (z>>zshift)*sC_hi + (z&((1<<zshift)-1))*sC_lo
template<bool OUT_BF16, bool BIAS, bool RELU, bool CSKIP, bool CKLIM>
__global__ __launch_bounds__(256, 4)
void gemm_bt_kernel(const bf16_t* __restrict__ A,
                    const bf16_t* __restrict__ Bt,
                    const float* __restrict__ bias,
                    void* __restrict__ Cv,
                    int M, int N, int K,
                    int lda, int ldb, int ldc,
                    long long sA, long long sB, long long sBias,
                    int zshift, long long sC_hi, long long sC_lo,
                    int msub_shift, long long msub_stride,
                    float alpha)
{
  const int zb = blockIdx.z;
  const int m0 = blockIdx.x * TM;
  const int n0 = blockIdx.y * TN;
  if (CSKIP && n0 > m0 + TM - 1) return;   // fully-masked causal tile
  int kend = K;
  if (CKLIM) { int ke = m0 + TM; kend = ke < K ? ke : K; }

  const bf16_t* Az = A + (long long)zb * sA;
  const bf16_t* Bz = Bt + (long long)zb * sB;
  const long long coff = ((long long)(zb >> zshift)) * sC_hi
                       + ((long long)(zb & ((1 << zshift) - 1))) * sC_lo;

  __shared__ __align__(16) bf16_t As[TM * BKK];
  __shared__ __align__(16) bf16_t Bs[TN * BKK];

  const int tid = threadIdx.x;
  const int wv = tid >> 6;
  const int lane = tid & 63;
  const int wm = (wv >> 1) * 64;
  const int wn = (wv & 1) * 64;
  const int fr = lane & 15;
  const int fg = lane >> 4;
  const int sw = fr & 7;              // read-side swizzle key

  f32x4_t acc[4][4];
  #pragma unroll
  for (int i = 0; i < 4; ++i)
    #pragma unroll
    for (int j = 0; j < 4; ++j)
      acc[i][j] = (f32x4_t){0.f, 0.f, 0.f, 0.f};

  // staging: tile 128x64 bf16 = 16 segs of 1KB; wave wv stages segs wv*4+s.
  // lane l -> row (l>>3), SWIZZLED col ((l&7)^(l>>3))*8, LDS dest linear l*16B.
  // => LDS(r, c) holds global col ((c/8) ^ (r&7))*8; read col ((kc*4+fg)^(fr&7))*8.
  const bf16_t* ga = Az + (long long)(m0 + (wv << 5) + (lane >> 3)) * lda
                   + (((lane & 7) ^ (lane >> 3)) << 3);
  const bf16_t* gb = Bz + (long long)(n0 + (wv << 5) + (lane >> 3)) * ldb
                   + (((lane & 7) ^ (lane >> 3)) << 3);

  for (int k0 = 0; k0 < kend; k0 += BKK) {
    #pragma unroll
    for (int s = 0; s < 4; ++s) {
      __builtin_amdgcn_global_load_lds(
        (const glb_u32*)(ga + (long long)s * 8 * lda + k0),
        (lds_u32*)(As + (wv * 4 + s) * 512), 16, 0, 0);
      __builtin_amdgcn_global_load_lds(
        (const glb_u32*)(gb + (long long)s * 8 * ldb + k0),
        (lds_u32*)(Bs + (wv * 4 + s) * 512), 16, 0, 0);
    }
    __syncthreads();
    #pragma unroll
    for (int kc = 0; kc < 2; ++kc) {
      const int ca = ((kc * 4 + fg) ^ sw) << 3;
      bf16x8_t af[4], bfr[4];
      #pragma unroll
      for (int i = 0; i < 4; ++i)
        af[i] = *(const bf16x8_t*)&As[(wm + i*16 + fr) * BKK + ca];
      #pragma unroll
      for (int j = 0; j < 4; ++j)
        bfr[j] = *(const bf16x8_t*)&Bs[(wn + j*16 + fr) * BKK + ca];
      #pragma unroll
      for (int i = 0; i < 4; ++i)
        #pragma unroll
        for (int j = 0; j < 4; ++j)
          acc[i][j] = __builtin_amdgcn_mfma_f32_16x16x32_bf16(af[i], bfr[j], acc[i][j], 0, 0, 0);
    }
    __syncthreads();   // all waves done reading before next stage overwrites
  }

  #pragma unroll
  for (int i = 0; i < 4; ++i) {
    #pragma unroll
    for (int e = 0; e < 4; ++e) {
      const int row = m0 + wm + i*16 + fg*4 + e;
      const long long ro = coff
        + ((long long)(row >> msub_shift)) * msub_stride
        + (long long)(row & ((1 << msub_shift) - 1)) * (long long)ldc;
      #pragma unroll
      for (int j = 0; j < 4; ++j) {
        const int col = n0 + wn + j*16 + fr;
        float v = acc[i][j][e] * alpha;
        if (BIAS) v += bias[(long long)zb * sBias + col];
        if (RELU) v = v > 0.f ? v : 0.f;
        if (OUT_BF16) ((bf16_t*)Cv)[ro + col] = (bf16_t)v;
        else          ((float*)Cv)[ro + col]  = v;
      }
    }
  }
}

// ---------------- transpose (+cast to bf16): out[C][R] = in[R][C] ----------------
template<typename TIN>
__global__ void transpose_kernel(const TIN* __restrict__ in, bf16_t* __restrict__ out,
                                 int R, int C, long long sIn, long long sOut)
{
  __shared__ float tile[32][33];
  const long long zi = (long long)blockIdx.z * sIn;
  const long long zo = (long long)blockIdx.z * sOut;
  const int c0 = blockIdx.x * 32, r0 = blockIdx.y * 32;
  const int tx = threadIdx.x, ty = threadIdx.y;  // 32 x 8
  #pragma unroll
  for (int i = 0; i < 4; ++i) {
    int r = r0 + ty + i*8;
    tile[ty + i*8][tx] = (float)in[zi + (long long)r * C + c0 + tx];
  }
  __syncthreads();
  #pragma unroll
  for (int i = 0; i < 4; ++i) {
    int c = c0 + ty + i*8;
    out[zo + (long long)c * R + r0 + tx] = (bf16_t)tile[tx][ty + i*8];
  }
}

// ---------------- q/k/v weight transpose for one layer, z=0..11 ----------------
__global__ void qkvT_kernel(const float* __restrict__ wq, const float* __restrict__ wk,
                            const float* __restrict__ wv, bf16_t* __restrict__ out, int layer)
{
  __shared__ float tile[32][33];
  const int z = blockIdx.z, op = z >> 2, h = z & 3;
  const float* src = (op == 0 ? wq : op == 1 ? wk : wv)
                   + ((long long)layer * NHEAD + h) * HD * HD;
  bf16_t* dst = out + (long long)z * HD * HD;
  const int c0 = blockIdx.x * 32, r0 = blockIdx.y * 32;
  const int tx = threadIdx.x, ty = threadIdx.y;
  #pragma unroll
  for (int i = 0; i < 4; ++i)
    tile[ty + i*8][tx] = src[(long long)(r0 + ty + i*8) * HD + c0 + tx];
  __syncthreads();
  #pragma unroll
  for (int i = 0; i < 4; ++i)
    dst[(long long)(c0 + ty + i*8) * HD + r0 + tx] = (bf16_t)tile[tx][ty + i*8];
}

// ---------------- two-source f32 -> bf16 convert (out laid [a | b]) ----------------
__global__ void convert2_kernel(const float* __restrict__ a, const float* __restrict__ b,
                                bf16_t* __restrict__ out, long long n)
{
  long long i = (long long)blockIdx.x * blockDim.x + threadIdx.x;
  long long stride = (long long)gridDim.x * blockDim.x;
  for (; i < 2*n; i += stride)
    out[i] = (bf16_t)(i < n ? a[i] : b[i - n]);
}

// ---------------- diagnostic fill ----------------
__global__ void fill_kernel(float* __restrict__ out, long long n, float v)
{
  long long i = (long long)blockIdx.x * blockDim.x + threadIdx.x;
  long long stride = (long long)gridDim.x * blockDim.x;
  for (; i < n; i += stride) out[i] = v;
}

// ---------------- positions: pos = cumsum(mask) - 1 ----------------
__global__ void pos_kernel(const int* __restrict__ mask, float* __restrict__ pos)
{
  __shared__ float scn[S_LEN];
  const int b = blockIdx.x, t = threadIdx.x;
  scn[t] = (float)(mask[b * S_LEN + t] != 0);
  __syncthreads();
  for (int off = 1; off < S_LEN; off <<= 1) {
    float add = (t >= off) ? scn[t - off] : 0.f;
    __syncthreads();
    scn[t] += add;
    __syncthreads();
  }
  pos[b * S_LEN + t] = scn[t] - 1.0f;
}

// ---------------- embedding + positional encoding ----------------
__global__ void embed_kernel(const int* __restrict__ ids, const int* __restrict__ mask,
                             const float* __restrict__ pos, const float* __restrict__ emb,
                             float* __restrict__ x, bf16_t* __restrict__ xb)
{
  const int idx = blockIdx.x * 256 + threadIdx.x;
  const int i = idx & 255;
  const int bs = idx >> 8;
  const int id = ids[bs];
  const float m = (float)(mask[bs] != 0);
  const float p = pos[bs];
  const float dv = __expf(-(float)(2 * i) * (9.210340371976184f / (float)HD));
  const float sv = __sinf(p * dv) * m;
  const float e0 = emb[id * HD + 2*i], e1 = emb[id * HD + 2*i + 1];
  const float x0 = e0 + sv, x1 = e1 + sv;
  x[(long long)bs * HD + 2*i]     = x0;
  x[(long long)bs * HD + 2*i + 1] = x1;
  xb[(long long)bs * HD + 2*i]     = (bf16_t)x0;
  xb[(long long)bs * HD + 2*i + 1] = (bf16_t)x1;
}

// ---------------- softmax, bf16 scores in-place -> bf16 P ----------------
__global__ void softmax_kernel(bf16_t* __restrict__ scP,
                               const int* __restrict__ mask, int pair0)
{
  const int s = blockIdx.x;
  const int pz = blockIdx.y;
  const int b = (pair0 + pz) >> 2;
  bf16_t* row = scP + ((long long)pz * S_LEN + s) * S_LEN;
  const bool qvalid = mask[b * S_LEN + s] != 0;
  const int tid = threadIdx.x;
  const int t0 = tid * 4;
  __shared__ float red[4];

  bf16x4_t raw = *(const bf16x4_t*)&row[t0];
  float v[4]; bool ok[4];
  #pragma unroll
  for (int j = 0; j < 4; ++j) {
    const int t = t0 + j;
    ok[j] = (t <= s) && (mask[b * S_LEN + t] != 0);
    v[j] = ok[j] ? (float)raw[j] : -INFINITY;
  }
  float mx = fmaxf(fmaxf(v[0], v[1]), fmaxf(v[2], v[3]));
  #pragma unroll
  for (int o = 32; o; o >>= 1) mx = fmaxf(mx, __shfl_xor(mx, o));
  if ((tid & 63) == 0) red[tid >> 6] = mx;
  __syncthreads();
  mx = fmaxf(fmaxf(red[0], red[1]), fmaxf(red[2], red[3]));
  __syncthreads();

  float e[4];
  float sum = 0.f;
  #pragma unroll
  for (int j = 0; j < 4; ++j) {
    e[j] = ok[j] ? __expf(v[j] - mx) : 0.f;
    sum += e[j];
  }
  #pragma unroll
  for (int o = 32; o; o >>= 1) sum += __shfl_xor(sum, o);
  if ((tid & 63) == 0) red[tid >> 6] = sum;
  __syncthreads();
  sum = red[0] + red[1] + red[2] + red[3];

  const float inv = (qvalid && sum > 0.f) ? 1.f / sum : 0.f;
  bf16x4_t o4;
  #pragma unroll
  for (int j = 0; j < 4; ++j) o4[j] = (bf16_t)(e[j] * inv);
  *(bf16x4_t*)&row[t0] = o4;
}

// ---------------- layernorm: x = LN(x + sum_i tparts[i] + bias); emit bf16 ----------------
__global__ void ln_kernel(float* __restrict__ x, const float* __restrict__ tparts,
                          int ns, long long pstride,
                          const float* __restrict__ bias,
                          const float* __restrict__ g, const float* __restrict__ b,
                          bf16_t* __restrict__ xb)
{
  __shared__ float red[4];
  const long long row = blockIdx.x;
  const int tid = threadIdx.x;  // 256, 2 elems each
  float v0 = x[row * HD + tid]       + bias[tid];
  float v1 = x[row * HD + tid + 256] + bias[tid + 256];
  for (int i = 0; i < ns; ++i) {
    v0 += tparts[i * pstride + row * HD + tid];
    v1 += tparts[i * pstride + row * HD + tid + 256];
  }
  float s = v0 + v1;
  #pragma unroll
  for (int o = 32; o; o >>= 1) s += __shfl_xor(s, o);
  if ((tid & 63) == 0) red[tid >> 6] = s;
  __syncthreads();
  const float mu = (red[0] + red[1] + red[2] + red[3]) * (1.f / (float)HD);
  __syncthreads();
  const float d0 = v0 - mu, d1 = v1 - mu;
  float q = d0 * d0 + d1 * d1;
  #pragma unroll
  for (int o = 32; o; o >>= 1) q += __shfl_xor(q, o);
  if ((tid & 63) == 0) red[tid >> 6] = q;
  __syncthreads();
  const float var = (red[0] + red[1] + red[2] + red[3]) * (1.f / (float)HD);
  const float inv = rsqrtf(var + 1e-5f);
  const float y0 = d0 * inv * g[tid]       + b[tid];
  const float y1 = d1 * inv * g[tid + 256] + b[tid + 256];
  x[row * HD + tid]       = y0;
  x[row * HD + tid + 256] = y1;
  xb[row * HD + tid]       = (bf16_t)y0;
  xb[row * HD + tid + 256] = (bf16_t)y1;
}

extern "C" void kernel_launch(void* const* d_in, const int* in_sizes, int n_in,
                              void* d_out, int out_size, void* d_ws, size_t ws_size,
                              hipStream_t stream)
{
  (void)in_sizes; (void)n_in;
  const int*   ids   = (const int*)d_in[0];
  const int*   amask = (const int*)d_in[1];
  const float* emb   = (const float*)d_in[2];
  const float* wq    = (const float*)d_in[3];
  const float* wk    = (const float*)d_in[4];
  const float* wv    = (const float*)d_in[5];
  const float* wo_w  = (const float*)d_in[6];
  const float* wo_b  = (const float*)d_in[7];
  const float* ln1_g = (const float*)d_in[8];
  const float* ln1_b = (const float*)d_in[9];
  const float* ff1_w = (const float*)d_in[10];
  const float* ff1_b = (const float*)d_in[11];
  const float* ff2_w = (const float*)d_in[12];
  const float* ff2_b = (const float*)d_in[13];
  const float* ln2_g = (const float*)d_in[14];
  const float* ln2_b = (const float*)d_in[15];
  const float* lm_w  = (const float*)d_in[16];

  const long long MROW = (long long)BATCH * S_LEN;   // 8192
  const size_t MBc = 1ull << 20;
  char* p = (char*)d_ws;
  auto alloc = [&](size_t bytes) { char* r = p; p += (bytes + 255) & ~(size_t)255; return r; };

  // persistent (~68 MB)
  float*  x     = (float*) alloc(MROW * HD * 4);                // 16 MB
  bf16_t* xb    = (bf16_t*)alloc(MROW * HD * 2);                // 8 MB
  bf16_t* ob    = (bf16_t*)alloc(MROW * (NHEAD*HD) * 2);        // 32 MB
  bf16_t* wqkvT = (bf16_t*)alloc(12LL * HD * HD * 2);           // 6 MB
  bf16_t* woT   = (bf16_t*)alloc((long long)HD * FFD * 2);      // 2 MB
  bf16_t* wff1  = (bf16_t*)alloc((long long)FFD * HD * 2);      // 2 MB
  bf16_t* wff2  = (bf16_t*)alloc((long long)HD * FFD * 2);      // 2 MB
  bf16_t* lmT   = (bf16_t*)alloc((long long)NTOK * HD * 2);
  float*  pos   = (float*) alloc(MROW * 4);

  const size_t used = (size_t)(p - (char*)d_ws);
  const size_t rem  = ws_size > used ? ws_size - used : 0;

  const int SK = 2;
  // attn region: P*(q1+k1+vT1)MB + P*2MB scores;  FF region: SK*16+32 = 64 MB
  int P = 0;
  if      (rem >= 80 * MBc) P = 16;   // attn 80 MB, FF 64 MB
  else if (rem >= 64 * MBc) P = 8;    // attn 40 MB, FF 64 MB
  if (P == 0) {
    fill_kernel<<<1024, 256, 0, stream>>>((float*)d_out, (long long)out_size,
                                          (float)(ws_size >> 20));
    return;
  }

  char* A = p;
  const long long pairE = (long long)S_LEN * HD;
  bf16_t* qc  = (bf16_t*)A;
  bf16_t* kc  = qc  + (long long)P * pairE;
  bf16_t* vTc = kc  + (long long)P * pairE;
  bf16_t* scb = vTc + (long long)P * pairE;        // bf16 scores, softmax in-place
  float*  tmp = (float*)A;                          // FF phase aliases (SK partials)
  bf16_t* ffb = (bf16_t*)(A + (size_t)SK * 16 * MBc);

  const dim3 tb(32, 8);
  transpose_kernel<float><<<dim3(4,16,1), tb, 0, stream>>>(lm_w, lmT, HD, NTOK, 0, 0);
  pos_kernel<<<BATCH, S_LEN, 0, stream>>>(amask, pos);
  embed_kernel<<<8192, 256, 0, stream>>>(ids, amask, pos, emb, x, xb);

  const int nch = 32 / P;
  const int bpc = P / NHEAD;

  for (int l = 0; l < NBLK; ++l) {
    qkvT_kernel<<<dim3(16,16,12), tb, 0, stream>>>(wq, wk, wv, wqkvT, l);
    transpose_kernel<float><<<dim3(16,64,1), tb, 0, stream>>>(
      wo_w + (long long)l*FFD*HD, woT, FFD, HD, 0, 0);
    convert2_kernel<<<2048, 256, 0, stream>>>(
      ff1_w + (long long)l*FFD*HD, ff2_w + (long long)l*HD*FFD, wff1, (long long)FFD*HD);

    for (int c = 0; c < nch; ++c) {
      const int b0 = c * bpc;
      const int pair0 = b0 * NHEAD;
      const int Mch = bpc * S_LEN;

      // fused q/k projections: z = op*4 + head (op in {q,k})
      gemm_bt_kernel<true,false,false,false,false><<<dim3(Mch/TM,4,8),256,0,stream>>>(
        xb + (long long)b0*S_LEN*HD, wqkvT, nullptr, qc, Mch, HD, HD, HD, HD, HD,
        0, (long long)HD*HD, 0,
        2, (long long)P*pairE, (long long)S_LEN*HD,
        10, (long long)NHEAD*S_LEN*HD, 1.f);

      // direct vT projection: vT[pair][d][t] = sum_h wvT[head][d][h] * xb[b,t,h]
      // A = wvT (4 heads stacked, M=2048), Bt = xb rows of batch (b0+z), N=1024
      gemm_bt_kernel<true,false,false,false,false><<<dim3(2048/TM,S_LEN/TN,bpc),256,0,stream>>>(
        wqkvT + 8LL*HD*HD, xb + (long long)b0*S_LEN*HD, nullptr, vTc,
        2048, S_LEN, HD, HD, HD, S_LEN,
        0, (long long)S_LEN*HD, 0,
        0, (long long)NHEAD*HD*S_LEN, 0,
        9, (long long)HD*S_LEN, 1.f);

      // scores = q @ k^T / sqrt(512) -> bf16 scb (causal tile skip)
      gemm_bt_kernel<true,false,false,true,false><<<dim3(8,8,P),256,0,stream>>>(
        qc, kc, nullptr, scb,
        S_LEN, S_LEN, HD, HD, HD, S_LEN,
        (long long)S_LEN*HD, (long long)S_LEN*HD, 0,
        30, 0, (long long)S_LEN*S_LEN,
        30, 0, 0.044194173824159216f);
      softmax_kernel<<<dim3(S_LEN,P),256,0,stream>>>(scb, amask, pair0);
      // o = P @ v   (causal k-limit)
      gemm_bt_kernel<true,false,false,false,true><<<dim3(8,4,P),256,0,stream>>>(
        scb, vTc, nullptr,
        ob + (long long)b0*S_LEN*(NHEAD*HD),
        S_LEN, HD, S_LEN, S_LEN, S_LEN, NHEAD*HD,
        (long long)S_LEN*S_LEN, (long long)HD*S_LEN, 0,
        2, (long long)S_LEN*NHEAD*HD, HD,
        30, 0, 1.f);
    }

    // mh = o @ wo (split-K=SK -> tmp partials; bias folded into LN)
    gemm_bt_kernel<false,false,false,false,false><<<dim3(64,4,SK),256,0,stream>>>(
      ob, woT, nullptr, tmp,
      (int)MROW, HD, (NHEAD*HD)/SK, NHEAD*HD, NHEAD*HD, HD,
      (NHEAD*HD)/SK, (NHEAD*HD)/SK, 0,
      0, (long long)MROW*HD, 0,
      30, 0, 1.f);
    ln_kernel<<<8192,256,0,stream>>>(x, tmp, SK, (long long)MROW*HD,
                                     wo_b + l*HD, ln1_g + l*HD, ln1_b + l*HD, xb);

    // ff1: relu(xb @ ff1^T + b1) -> ffb (bf16)
    gemm_bt_kernel<true,true,true,false,false><<<dim3(64,16,1),256,0,stream>>>(
      xb, wff1, ff1_b + l*FFD, ffb,
      (int)MROW, FFD, HD, HD, HD, FFD,
      0, 0, 0, 30, 0, 0, 30, 0, 1.f);
    // ff2 (split-K=SK)
    gemm_bt_kernel<false,false,false,false,false><<<dim3(64,4,SK),256,0,stream>>>(
      ffb, wff2, nullptr, tmp,
      (int)MROW, HD, FFD/SK, FFD, FFD, HD,
      FFD/SK, FFD/SK, 0,
      0, (long long)MROW*HD, 0,
      30, 0, 1.f);
    ln_kernel<<<8192,256,0,stream>>>(x, tmp, SK, (long long)MROW*HD,
                                     ff2_b + l*HD, ln2_g + l*HD, ln2_b + l*HD, xb);
  }

  // lm head -> d_out (f32)
  gemm_bt_kernel<false,false,false,false,false><<<dim3(64,1,1),256,0,stream>>>(
    xb, lmT, nullptr, (float*)d_out,
    (int)MROW, NTOK, HD, HD, HD, NTOK,
    0, 0, 0, 30, 0, 0, 30, 0, 1.f);
}

// Round 6
// 993.719 us; speedup vs baseline: 2.0837x; 1.0135x over previous
//
#include <hip/hip_runtime.h>
#include <hip/hip_bf16.h>

#define S_LEN 1024
#define BATCH 8
#define HD 512
#define FFD 2048
#define NHEAD 4
#define NBLK 3
#define NTOK 128

typedef __bf16 bf16_t;
typedef __bf16 bf16x4_t __attribute__((ext_vector_type(4)));
typedef __bf16 bf16x8_t __attribute__((ext_vector_type(8)));
typedef float f32x4_t __attribute__((ext_vector_type(4)));

typedef __attribute__((address_space(3))) uint32_t lds_u32;
typedef __attribute__((address_space(1))) uint32_t glb_u32;

// phase boundary: pin instruction movement, then raw barrier (no waitcnt drain)
#define PB() do { __builtin_amdgcn_sched_barrier(0); __builtin_amdgcn_s_barrier(); } while (0)

// ---- LDS fragment read: NI frags of 16 rows from row0, XOR-swizzled chunks ----
template<int NI>
__device__ __forceinline__ void ldsread(const bf16_t* __restrict__ buf, int row0,
                                        int fr, int fg, int sw, bf16x8_t (&dst)[NI][2]) {
  #pragma unroll
  for (int i = 0; i < NI; ++i)
    #pragma unroll
    for (int ks = 0; ks < 2; ++ks)
      dst[i][ks] = *(const bf16x8_t*)&buf[(row0 + i*16 + fr)*64 + (((ks*4 + fg) ^ sw) << 3)];
}

// ---- one C-quadrant x K=64: 16 MFMA wrapped in setprio (T5) ----
template<int IB, int JB>
__device__ __forceinline__ void mquad(f32x4_t (&acc)[8][4],
                                      const bf16x8_t (&af)[4][2], const bf16x8_t (&bf)[2][2]) {
  __builtin_amdgcn_s_setprio(1);
  #pragma unroll
  for (int ks = 0; ks < 2; ++ks)
    #pragma unroll
    for (int i = 0; i < 4; ++i)
      #pragma unroll
      for (int j = 0; j < 2; ++j)
        acc[IB+i][JB+j] = __builtin_amdgcn_mfma_f32_16x16x32_bf16(af[i][ks], bf[j][ks], acc[IB+i][JB+j], 0, 0, 0);
  __builtin_amdgcn_s_setprio(0);
}

// ================= 256x256 8-phase GEMM (guide §5 template, plain HIP) =================
// C = alpha * A @ Bt^T (+bias)(+relu).  A:[M,K] bf16 (lda), Bt:[N,K] bf16 (ldb).
// 512 thr = 8 waves (2M x 4N), per-wave C 128x64. BK=64, 2-buffer 128KiB LDS.
// Phases per K-tile t: P0{rdA_lo+rdB_lo | stage B0(t+1)} P1{rdA_hi+rdB_hi | stage B1(t+1)}
// P2{stage A0(t+2)} P3{stage A1(t+2), vmcnt(4)}. Each phase: PB; MFMA quad; PB.
// Safety (verified by issue-order trace): any LDS region is overwritten >=1 full
// phase after its last read completed; vmcnt(4) = allow newest 2 stages (4 loads).
template<bool OUT_BF16, bool BIAS, bool RELU, bool CSKIP, bool CKLIM>
__global__ __launch_bounds__(512, 2)
void gemm256_kernel(const bf16_t* __restrict__ A,
                    const bf16_t* __restrict__ Bt,
                    const float* __restrict__ bias,
                    void* __restrict__ Cv,
                    int M, int N, int K,
                    int lda, int ldb, int ldc,
                    long long sA, long long sB, long long sBias,
                    int zshift, long long sC_hi, long long sC_lo,
                    int msub_shift, long long msub_stride,
                    float alpha)
{
  const int zb = blockIdx.z;
  const int m0 = blockIdx.x * 256;
  const int n0 = blockIdx.y * 256;
  if (CSKIP && n0 > m0 + 255) return;
  int kend = K;
  if (CKLIM) { int ke = m0 + 256; kend = ke < K ? ke : K; }
  const int nt = kend >> 6;

  const bf16_t* Az = A + (long long)zb * sA;
  const bf16_t* Bz = Bt + (long long)zb * sB;
  const long long coff = ((long long)(zb >> zshift)) * sC_hi
                       + ((long long)(zb & ((1 << zshift) - 1))) * sC_lo;

  __shared__ __align__(16) bf16_t As[2][256 * 64];
  __shared__ __align__(16) bf16_t Bs[2][256 * 64];

  const int tid = threadIdx.x;          // 0..511
  const int lane = tid & 63;
  const int w = tid >> 6;               // 0..7
  const int wm = (w >> 2) * 128;        // 0,128
  const int wn = (w & 3) * 64;          // 0,64,128,192
  const int fr = lane & 15;
  const int fg = lane >> 4;
  const int sw = fr & 7;

  // staging: thread -> row_local = s*64 + (tid>>3), chunk (tid&7); swizzled src col
  const int srow = tid >> 3;            // 0..63
  const int scol8 = tid & 7;
  const int gswz = ((scol8 ^ (srow & 7)) << 3);

  f32x4_t acc[8][4];
  #pragma unroll
  for (int i = 0; i < 8; ++i)
    #pragma unroll
    for (int j = 0; j < 4; ++j)
      acc[i][j] = (f32x4_t){0.f, 0.f, 0.f, 0.f};

  // stage one 128x64 half-tile (2 global_load_lds/thread). h:0=A0,1=A1,2=B0,3=B1
  auto stage_half = [&](int buf, int kt, int h) {
    if (h < 2) {
      const bf16_t* g = Az + (long long)(m0 + h*128 + srow) * lda + (kt << 6) + gswz;
      bf16_t* l = &As[buf][(h*128 + srow) * 64 + (scol8 << 3)];
      __builtin_amdgcn_global_load_lds((const glb_u32*)g, (lds_u32*)l, 16, 0, 0);
      __builtin_amdgcn_global_load_lds((const glb_u32*)(g + 64LL*lda), (lds_u32*)(l + 64*64), 16, 0, 0);
    } else {
      const int hh = h - 2;
      const bf16_t* g = Bz + (long long)(n0 + hh*128 + srow) * ldb + (kt << 6) + gswz;
      bf16_t* l = &Bs[buf][(hh*128 + srow) * 64 + (scol8 << 3)];
      __builtin_amdgcn_global_load_lds((const glb_u32*)g, (lds_u32*)l, 16, 0, 0);
      __builtin_amdgcn_global_load_lds((const glb_u32*)(g + 64LL*ldb), (lds_u32*)(l + 64*64), 16, 0, 0);
    }
  };

  // prologue: full t0 + A-halves of t1; wait t0 (allow t1's 2 stages in flight)
  stage_half(0, 0, 0); stage_half(0, 0, 1); stage_half(0, 0, 2); stage_half(0, 0, 3);
  if (nt > 1) { stage_half(1, 1, 0); stage_half(1, 1, 1); }
  if (nt > 1) asm volatile("s_waitcnt vmcnt(4)" ::: "memory");
  else        asm volatile("s_waitcnt vmcnt(0)" ::: "memory");
  PB();

  for (int t = 0; t < nt; ++t) {
    const int cur = t & 1;
    const bf16_t* Ac = &As[cur][0];
    const bf16_t* Bc = &Bs[cur][0];
    bf16x8_t a0[4][2], a1[4][2], b0[2][2], b1[2][2];
    // P0: read A rows [wm..wm+63], B rows [wn..wn+31]; stage B0(t+1)
    ldsread<4>(Ac, wm, fr, fg, sw, a0);
    ldsread<2>(Bc, wn, fr, fg, sw, b0);
    if (t + 1 < nt) stage_half(cur ^ 1, t + 1, 2);
    PB();
    mquad<0, 0>(acc, a0, b0);
    PB();
    // P1: read A rows [wm+64..127], B rows [wn+32..63]; stage B1(t+1)
    ldsread<4>(Ac, wm + 64, fr, fg, sw, a1);
    ldsread<2>(Bc, wn + 32, fr, fg, sw, b1);
    if (t + 1 < nt) stage_half(cur ^ 1, t + 1, 3);
    PB();
    mquad<4, 2>(acc, a1, b1);
    PB();
    // P2: stage A0(t+2)  (tile t's LDS reads all completed end of P1)
    if (t + 2 < nt) stage_half(cur, t + 2, 0);
    PB();
    mquad<0, 2>(acc, a0, b1);
    PB();
    // P3: stage A1(t+2); counted wait: tile t+1 landed, newest 2 stages fly
    if (t + 2 < nt) {
      stage_half(cur, t + 2, 1);
      asm volatile("s_waitcnt vmcnt(4)" ::: "memory");
    } else {
      asm volatile("s_waitcnt vmcnt(0)" ::: "memory");
    }
    PB();
    mquad<4, 0>(acc, a1, b0);
    PB();
  }

  #pragma unroll
  for (int i = 0; i < 8; ++i) {
    #pragma unroll
    for (int e = 0; e < 4; ++e) {
      const int row = m0 + wm + i*16 + fg*4 + e;
      const long long ro = coff
        + ((long long)(row >> msub_shift)) * msub_stride
        + (long long)(row & ((1 << msub_shift) - 1)) * (long long)ldc;
      #pragma unroll
      for (int j = 0; j < 4; ++j) {
        const int col = n0 + wn + j*16 + fr;
        float v = acc[i][j][e] * alpha;
        if (BIAS) v += bias[(long long)zb * sBias + col];
        if (RELU) v = v > 0.f ? v : 0.f;
        if (OUT_BF16) ((bf16_t*)Cv)[ro + col] = (bf16_t)v;
        else          ((float*)Cv)[ro + col]  = v;
      }
    }
  }
}

// ================= 128x128 m97-style GEMM (kept for lm head, N=128) =================
template<bool OUT_BF16, bool BIAS, bool RELU, bool CSKIP, bool CKLIM>
__global__ __launch_bounds__(256, 4)
void gemm_bt_kernel(const bf16_t* __restrict__ A,
                    const bf16_t* __restrict__ Bt,
                    const float* __restrict__ bias,
                    void* __restrict__ Cv,
                    int M, int N, int K,
                    int lda, int ldb, int ldc,
                    long long sA, long long sB, long long sBias,
                    int zshift, long long sC_hi, long long sC_lo,
                    int msub_shift, long long msub_stride,
                    float alpha)
{
  const int zb = blockIdx.z;
  const int m0 = blockIdx.x * 128;
  const int n0 = blockIdx.y * 128;
  if (CSKIP && n0 > m0 + 127) return;
  int kend = K;
  if (CKLIM) { int ke = m0 + 128; kend = ke < K ? ke : K; }

  const bf16_t* Az = A + (long long)zb * sA;
  const bf16_t* Bz = Bt + (long long)zb * sB;
  const long long coff = ((long long)(zb >> zshift)) * sC_hi
                       + ((long long)(zb & ((1 << zshift) - 1))) * sC_lo;

  __shared__ __align__(16) bf16_t As[128 * 64];
  __shared__ __align__(16) bf16_t Bs[128 * 64];

  const int tid = threadIdx.x;
  const int wv = tid >> 6;
  const int lane = tid & 63;
  const int wm = (wv >> 1) * 64;
  const int wn = (wv & 1) * 64;
  const int fr = lane & 15;
  const int fg = lane >> 4;
  const int sw = fr & 7;

  f32x4_t acc[4][4];
  #pragma unroll
  for (int i = 0; i < 4; ++i)
    #pragma unroll
    for (int j = 0; j < 4; ++j)
      acc[i][j] = (f32x4_t){0.f, 0.f, 0.f, 0.f};

  const bf16_t* ga = Az + (long long)(m0 + (wv << 5) + (lane >> 3)) * lda
                   + (((lane & 7) ^ (lane >> 3)) << 3);
  const bf16_t* gb = Bz + (long long)(n0 + (wv << 5) + (lane >> 3)) * ldb
                   + (((lane & 7) ^ (lane >> 3)) << 3);

  for (int k0 = 0; k0 < kend; k0 += 64) {
    #pragma unroll
    for (int s = 0; s < 4; ++s) {
      __builtin_amdgcn_global_load_lds(
        (const glb_u32*)(ga + (long long)s * 8 * lda + k0),
        (lds_u32*)(As + (wv * 4 + s) * 512), 16, 0, 0);
      __builtin_amdgcn_global_load_lds(
        (const glb_u32*)(gb + (long long)s * 8 * ldb + k0),
        (lds_u32*)(Bs + (wv * 4 + s) * 512), 16, 0, 0);
    }
    __syncthreads();
    #pragma unroll
    for (int kc = 0; kc < 2; ++kc) {
      const int ca = ((kc * 4 + fg) ^ sw) << 3;
      bf16x8_t af[4], bfr[4];
      #pragma unroll
      for (int i = 0; i < 4; ++i)
        af[i] = *(const bf16x8_t*)&As[(wm + i*16 + fr) * 64 + ca];
      #pragma unroll
      for (int j = 0; j < 4; ++j)
        bfr[j] = *(const bf16x8_t*)&Bs[(wn + j*16 + fr) * 64 + ca];
      #pragma unroll
      for (int i = 0; i < 4; ++i)
        #pragma unroll
        for (int j = 0; j < 4; ++j)
          acc[i][j] = __builtin_amdgcn_mfma_f32_16x16x32_bf16(af[i], bfr[j], acc[i][j], 0, 0, 0);
    }
    __syncthreads();
  }

  #pragma unroll
  for (int i = 0; i < 4; ++i) {
    #pragma unroll
    for (int e = 0; e < 4; ++e) {
      const int row = m0 + wm + i*16 + fg*4 + e;
      const long long ro = coff
        + ((long long)(row >> msub_shift)) * msub_stride
        + (long long)(row & ((1 << msub_shift) - 1)) * (long long)ldc;
      #pragma unroll
      for (int j = 0; j < 4; ++j) {
        const int col = n0 + wn + j*16 + fr;
        float v = acc[i][j][e] * alpha;
        if (BIAS) v += bias[(long long)zb * sBias + col];
        if (RELU) v = v > 0.f ? v : 0.f;
        if (OUT_BF16) ((bf16_t*)Cv)[ro + col] = (bf16_t)v;
        else          ((float*)Cv)[ro + col]  = v;
      }
    }
  }
}

// ---------------- transpose (+cast to bf16): out[C][R] = in[R][C] ----------------
template<typename TIN>
__global__ void transpose_kernel(const TIN* __restrict__ in, bf16_t* __restrict__ out,
                                 int R, int C, long long sIn, long long sOut)
{
  __shared__ float tile[32][33];
  const long long zi = (long long)blockIdx.z * sIn;
  const long long zo = (long long)blockIdx.z * sOut;
  const int c0 = blockIdx.x * 32, r0 = blockIdx.y * 32;
  const int tx = threadIdx.x, ty = threadIdx.y;  // 32 x 8
  #pragma unroll
  for (int i = 0; i < 4; ++i) {
    int r = r0 + ty + i*8;
    tile[ty + i*8][tx] = (float)in[zi + (long long)r * C + c0 + tx];
  }
  __syncthreads();
  #pragma unroll
  for (int i = 0; i < 4; ++i) {
    int c = c0 + ty + i*8;
    out[zo + (long long)c * R + r0 + tx] = (bf16_t)tile[tx][ty + i*8];
  }
}

// ---------------- q/k/v weight transpose for one layer, z=0..11 ----------------
__global__ void qkvT_kernel(const float* __restrict__ wq, const float* __restrict__ wk,
                            const float* __restrict__ wv, bf16_t* __restrict__ out, int layer)
{
  __shared__ float tile[32][33];
  const int z = blockIdx.z, op = z >> 2, h = z & 3;
  const float* src = (op == 0 ? wq : op == 1 ? wk : wv)
                   + ((long long)layer * NHEAD + h) * HD * HD;
  bf16_t* dst = out + (long long)z * HD * HD;
  const int c0 = blockIdx.x * 32, r0 = blockIdx.y * 32;
  const int tx = threadIdx.x, ty = threadIdx.y;
  #pragma unroll
  for (int i = 0; i < 4; ++i)
    tile[ty + i*8][tx] = src[(long long)(r0 + ty + i*8) * HD + c0 + tx];
  __syncthreads();
  #pragma unroll
  for (int i = 0; i < 4; ++i)
    dst[(long long)(c0 + ty + i*8) * HD + r0 + tx] = (bf16_t)tile[tx][ty + i*8];
}

// ---------------- two-source f32 -> bf16 convert (out laid [a | b]) ----------------
__global__ void convert2_kernel(const float* __restrict__ a, const float* __restrict__ b,
                                bf16_t* __restrict__ out, long long n)
{
  long long i = (long long)blockIdx.x * blockDim.x + threadIdx.x;
  long long stride = (long long)gridDim.x * blockDim.x;
  for (; i < 2*n; i += stride)
    out[i] = (bf16_t)(i < n ? a[i] : b[i - n]);
}

// ---------------- diagnostic fill ----------------
__global__ void fill_kernel(float* __restrict__ out, long long n, float v)
{
  long long i = (long long)blockIdx.x * blockDim.x + threadIdx.x;
  long long stride = (long long)gridDim.x * blockDim.x;
  for (; i < n; i += stride) out[i] = v;
}

// ---------------- positions: pos = cumsum(mask) - 1 ----------------
__global__ void pos_kernel(const int* __restrict__ mask, float* __restrict__ pos)
{
  __shared__ float scn[S_LEN];
  const int b = blockIdx.x, t = threadIdx.x;
  scn[t] = (float)(mask[b * S_LEN + t] != 0);
  __syncthreads();
  for (int off = 1; off < S_LEN; off <<= 1) {
    float add = (t >= off) ? scn[t - off] : 0.f;
    __syncthreads();
    scn[t] += add;
    __syncthreads();
  }
  pos[b * S_LEN + t] = scn[t] - 1.0f;
}

// ---------------- embedding + positional encoding ----------------
__global__ void embed_kernel(const int* __restrict__ ids, const int* __restrict__ mask,
                             const float* __restrict__ pos, const float* __restrict__ emb,
                             float* __restrict__ x, bf16_t* __restrict__ xb)
{
  const int idx = blockIdx.x * 256 + threadIdx.x;
  const int i = idx & 255;
  const int bs = idx >> 8;
  const int id = ids[bs];
  const float m = (float)(mask[bs] != 0);
  const float p = pos[bs];
  const float dv = __expf(-(float)(2 * i) * (9.210340371976184f / (float)HD));
  const float sv = __sinf(p * dv) * m;
  const float e0 = emb[id * HD + 2*i], e1 = emb[id * HD + 2*i + 1];
  const float x0 = e0 + sv, x1 = e1 + sv;
  x[(long long)bs * HD + 2*i]     = x0;
  x[(long long)bs * HD + 2*i + 1] = x1;
  xb[(long long)bs * HD + 2*i]     = (bf16_t)x0;
  xb[(long long)bs * HD + 2*i + 1] = (bf16_t)x1;
}

// ---------------- softmax, bf16 scores in-place -> bf16 P ----------------
__global__ void softmax_kernel(bf16_t* __restrict__ scP,
                               const int* __restrict__ mask, int pair0)
{
  const int s = blockIdx.x;
  const int pz = blockIdx.y;
  const int b = (pair0 + pz) >> 2;
  bf16_t* row = scP + ((long long)pz * S_LEN + s) * S_LEN;
  const bool qvalid = mask[b * S_LEN + s] != 0;
  const int tid = threadIdx.x;
  const int t0 = tid * 4;
  __shared__ float red[4];

  bf16x4_t raw = *(const bf16x4_t*)&row[t0];
  float v[4]; bool ok[4];
  #pragma unroll
  for (int j = 0; j < 4; ++j) {
    const int t = t0 + j;
    ok[j] = (t <= s) && (mask[b * S_LEN + t] != 0);
    v[j] = ok[j] ? (float)raw[j] : -INFINITY;
  }
  float mx = fmaxf(fmaxf(v[0], v[1]), fmaxf(v[2], v[3]));
  #pragma unroll
  for (int o = 32; o; o >>= 1) mx = fmaxf(mx, __shfl_xor(mx, o));
  if ((tid & 63) == 0) red[tid >> 6] = mx;
  __syncthreads();
  mx = fmaxf(fmaxf(red[0], red[1]), fmaxf(red[2], red[3]));
  __syncthreads();

  float e[4];
  float sum = 0.f;
  #pragma unroll
  for (int j = 0; j < 4; ++j) {
    e[j] = ok[j] ? __expf(v[j] - mx) : 0.f;
    sum += e[j];
  }
  #pragma unroll
  for (int o = 32; o; o >>= 1) sum += __shfl_xor(sum, o);
  if ((tid & 63) == 0) red[tid >> 6] = sum;
  __syncthreads();
  sum = red[0] + red[1] + red[2] + red[3];

  const float inv = (qvalid && sum > 0.f) ? 1.f / sum : 0.f;
  bf16x4_t o4;
  #pragma unroll
  for (int j = 0; j < 4; ++j) o4[j] = (bf16_t)(e[j] * inv);
  *(bf16x4_t*)&row[t0] = o4;
}

// ---------------- layernorm: x = LN(x + sum_i tparts[i] + bias); emit bf16 ----------------
__global__ void ln_kernel(float* __restrict__ x, const float* __restrict__ tparts,
                          int ns, long long pstride,
                          const float* __restrict__ bias,
                          const float* __restrict__ g, const float* __restrict__ b,
                          bf16_t* __restrict__ xb)
{
  __shared__ float red[4];
  const long long row = blockIdx.x;
  const int tid = threadIdx.x;  // 256, 2 elems each
  float v0 = x[row * HD + tid]       + bias[tid];
  float v1 = x[row * HD + tid + 256] + bias[tid + 256];
  for (int i = 0; i < ns; ++i) {
    v0 += tparts[i * pstride + row * HD + tid];
    v1 += tparts[i * pstride + row * HD + tid + 256];
  }
  float s = v0 + v1;
  #pragma unroll
  for (int o = 32; o; o >>= 1) s += __shfl_xor(s, o);
  if ((tid & 63) == 0) red[tid >> 6] = s;
  __syncthreads();
  const float mu = (red[0] + red[1] + red[2] + red[3]) * (1.f / (float)HD);
  __syncthreads();
  const float d0 = v0 - mu, d1 = v1 - mu;
  float q = d0 * d0 + d1 * d1;
  #pragma unroll
  for (int o = 32; o; o >>= 1) q += __shfl_xor(q, o);
  if ((tid & 63) == 0) red[tid >> 6] = q;
  __syncthreads();
  const float var = (red[0] + red[1] + red[2] + red[3]) * (1.f / (float)HD);
  const float inv = rsqrtf(var + 1e-5f);
  const float y0 = d0 * inv * g[tid]       + b[tid];
  const float y1 = d1 * inv * g[tid + 256] + b[tid + 256];
  x[row * HD + tid]       = y0;
  x[row * HD + tid + 256] = y1;
  xb[row * HD + tid]       = (bf16_t)y0;
  xb[row * HD + tid + 256] = (bf16_t)y1;
}

extern "C" void kernel_launch(void* const* d_in, const int* in_sizes, int n_in,
                              void* d_out, int out_size, void* d_ws, size_t ws_size,
                              hipStream_t stream)
{
  (void)in_sizes; (void)n_in;
  const int*   ids   = (const int*)d_in[0];
  const int*   amask = (const int*)d_in[1];
  const float* emb   = (const float*)d_in[2];
  const float* wq    = (const float*)d_in[3];
  const float* wk    = (const float*)d_in[4];
  const float* wv    = (const float*)d_in[5];
  const float* wo_w  = (const float*)d_in[6];
  const float* wo_b  = (const float*)d_in[7];
  const float* ln1_g = (const float*)d_in[8];
  const float* ln1_b = (const float*)d_in[9];
  const float* ff1_w = (const float*)d_in[10];
  const float* ff1_b = (const float*)d_in[11];
  const float* ff2_w = (const float*)d_in[12];
  const float* ff2_b = (const float*)d_in[13];
  const float* ln2_g = (const float*)d_in[14];
  const float* ln2_b = (const float*)d_in[15];
  const float* lm_w  = (const float*)d_in[16];

  const long long MROW = (long long)BATCH * S_LEN;   // 8192
  const size_t MBc = 1ull << 20;
  char* p = (char*)d_ws;
  auto alloc = [&](size_t bytes) { char* r = p; p += (bytes + 255) & ~(size_t)255; return r; };

  // persistent (~68 MB)
  float*  x     = (float*) alloc(MROW * HD * 4);                // 16 MB
  bf16_t* xb    = (bf16_t*)alloc(MROW * HD * 2);                // 8 MB
  bf16_t* ob    = (bf16_t*)alloc(MROW * (NHEAD*HD) * 2);        // 32 MB
  bf16_t* wqkvT = (bf16_t*)alloc(12LL * HD * HD * 2);           // 6 MB
  bf16_t* woT   = (bf16_t*)alloc((long long)HD * FFD * 2);      // 2 MB
  bf16_t* wff1  = (bf16_t*)alloc((long long)FFD * HD * 2);      // 2 MB
  bf16_t* wff2  = (bf16_t*)alloc((long long)HD * FFD * 2);      // 2 MB
  bf16_t* lmT   = (bf16_t*)alloc((long long)NTOK * HD * 2);
  float*  pos   = (float*) alloc(MROW * 4);

  const size_t used = (size_t)(p - (char*)d_ws);
  const size_t rem  = ws_size > used ? ws_size - used : 0;

  // tiers: attn region P*(q1+k1+vT1)MB + P*2MB scores;  FF region SK*16+32 MB (aliased)
  int P = 0, SK = 2;
  if      (rem >= 160 * MBc) { P = 32; SK = 4; }  // attn 160 MB, FF 96 MB
  else if (rem >= 64 * MBc)  { P = 8;  SK = 2; }  // attn 40 MB, FF 64 MB
  if (P == 0) {
    fill_kernel<<<1024, 256, 0, stream>>>((float*)d_out, (long long)out_size,
                                          (float)(ws_size >> 20));
    return;
  }

  char* A = p;
  const long long pairE = (long long)S_LEN * HD;
  bf16_t* qc  = (bf16_t*)A;
  bf16_t* kc  = qc  + (long long)P * pairE;
  bf16_t* vTc = kc  + (long long)P * pairE;
  bf16_t* scb = vTc + (long long)P * pairE;        // bf16 scores, softmax in-place
  float*  tmp = (float*)A;                          // FF phase aliases (SK partials)
  bf16_t* ffb = (bf16_t*)(A + (size_t)SK * 16 * MBc);

  const dim3 tb(32, 8);
  transpose_kernel<float><<<dim3(4,16,1), tb, 0, stream>>>(lm_w, lmT, HD, NTOK, 0, 0);
  pos_kernel<<<BATCH, S_LEN, 0, stream>>>(amask, pos);
  embed_kernel<<<8192, 256, 0, stream>>>(ids, amask, pos, emb, x, xb);

  const int nch = 32 / P;
  const int bpc = P / NHEAD;

  for (int l = 0; l < NBLK; ++l) {
    qkvT_kernel<<<dim3(16,16,12), tb, 0, stream>>>(wq, wk, wv, wqkvT, l);
    transpose_kernel<float><<<dim3(16,64,1), tb, 0, stream>>>(
      wo_w + (long long)l*FFD*HD, woT, FFD, HD, 0, 0);
    convert2_kernel<<<2048, 256, 0, stream>>>(
      ff1_w + (long long)l*FFD*HD, ff2_w + (long long)l*HD*FFD, wff1, (long long)FFD*HD);

    for (int c = 0; c < nch; ++c) {
      const int b0 = c * bpc;
      const int pair0 = b0 * NHEAD;
      const int Mch = bpc * S_LEN;

      // fused q/k projections: z = op*4 + head (op in {q,k})
      gemm256_kernel<true,false,false,false,false><<<dim3(Mch/256,2,8),512,0,stream>>>(
        xb + (long long)b0*S_LEN*HD, wqkvT, nullptr, qc, Mch, HD, HD, HD, HD, HD,
        0, (long long)HD*HD, 0,
        2, (long long)P*pairE, (long long)S_LEN*HD,
        10, (long long)NHEAD*S_LEN*HD, 1.f);

      // direct vT projection: vT[pair][d][t] = sum_h wvT[head][d][h] * xb[b,t,h]
      gemm256_kernel<true,false,false,false,false><<<dim3(8,4,bpc),512,0,stream>>>(
        wqkvT + 8LL*HD*HD, xb + (long long)b0*S_LEN*HD, nullptr, vTc,
        2048, S_LEN, HD, HD, HD, S_LEN,
        0, (long long)S_LEN*HD, 0,
        0, (long long)NHEAD*HD*S_LEN, 0,
        9, (long long)HD*S_LEN, 1.f);

      // scores = q @ k^T / sqrt(512) -> bf16 scb (causal tile skip)
      gemm256_kernel<true,false,false,true,false><<<dim3(4,4,P),512,0,stream>>>(
        qc, kc, nullptr, scb,
        S_LEN, S_LEN, HD, HD, HD, S_LEN,
        (long long)S_LEN*HD, (long long)S_LEN*HD, 0,
        30, 0, (long long)S_LEN*S_LEN,
        30, 0, 0.044194173824159216f);
      softmax_kernel<<<dim3(S_LEN,P),256,0,stream>>>(scb, amask, pair0);
      // o = P @ v   (causal k-limit)
      gemm256_kernel<true,false,false,false,true><<<dim3(4,2,P),512,0,stream>>>(
        scb, vTc, nullptr,
        ob + (long long)b0*S_LEN*(NHEAD*HD),
        S_LEN, HD, S_LEN, S_LEN, S_LEN, NHEAD*HD,
        (long long)S_LEN*S_LEN, (long long)HD*S_LEN, 0,
        2, (long long)S_LEN*NHEAD*HD, HD,
        30, 0, 1.f);
    }

    // mh = o @ wo (split-K=SK -> tmp partials; bias folded into LN)
    gemm256_kernel<false,false,false,false,false><<<dim3(32,2,SK),512,0,stream>>>(
      ob, woT, nullptr, tmp,
      (int)MROW, HD, (NHEAD*HD)/SK, NHEAD*HD, NHEAD*HD, HD,
      (NHEAD*HD)/SK, (NHEAD*HD)/SK, 0,
      0, (long long)MROW*HD, 0,
      30, 0, 1.f);
    ln_kernel<<<8192,256,0,stream>>>(x, tmp, SK, (long long)MROW*HD,
                                     wo_b + l*HD, ln1_g + l*HD, ln1_b + l*HD, xb);

    // ff1: relu(xb @ ff1^T + b1) -> ffb (bf16)
    gemm256_kernel<true,true,true,false,false><<<dim3(32,8,1),512,0,stream>>>(
      xb, wff1, ff1_b + l*FFD, ffb,
      (int)MROW, FFD, HD, HD, HD, FFD,
      0, 0, 0, 30, 0, 0, 30, 0, 1.f);
    // ff2 (split-K=SK)
    gemm256_kernel<false,false,false,false,false><<<dim3(32,2,SK),512,0,stream>>>(
      ffb, wff2, nullptr, tmp,
      (int)MROW, HD, FFD/SK, FFD, FFD, HD,
      FFD/SK, FFD/SK, 0,
      0, (long long)MROW*HD, 0,
      30, 0, 1.f);
    ln_kernel<<<8192,256,0,stream>>>(x, tmp, SK, (long long)MROW*HD,
                                     ff2_b + l*HD, ln2_g + l*HD, ln2_b + l*HD, xb);
  }

  // lm head -> d_out (f32), N=128 -> 128-tile kernel
  gemm_bt_kernel<false,false,false,false,false><<<dim3(64,1,1),256,0,stream>>>(
    xb, lmT, nullptr, (float*)d_out,
    (int)MROW, NTOK, HD, HD, HD, NTOK,
    0, 0, 0, 30, 0, 0, 30, 0, 1.f);
}

// Round 7
// 899.414 us; speedup vs baseline: 2.3022x; 1.1049x over previous
//
#include <hip/hip_runtime.h>
#include <hip/hip_bf16.h>

#define S_LEN 1024
#define BATCH 8
#define HD 512
#define FFD 2048
#define NHEAD 4
#define NBLK 3
#define NTOK 128

typedef __bf16 bf16_t;
typedef __bf16 bf16x4_t __attribute__((ext_vector_type(4)));
typedef __bf16 bf16x8_t __attribute__((ext_vector_type(8)));
typedef float f32x4_t __attribute__((ext_vector_type(4)));

typedef __attribute__((address_space(3))) uint32_t lds_u32;
typedef __attribute__((address_space(1))) uint32_t glb_u32;

// ---- LDS fragment read: NI frags of 16 rows from row0, XOR-swizzled chunks ----
template<int NI>
__device__ __forceinline__ void ldsread(const bf16_t* __restrict__ buf, int row0,
                                        int fr, int fg, int sw, bf16x8_t (&dst)[NI][2]) {
  #pragma unroll
  for (int i = 0; i < NI; ++i)
    #pragma unroll
    for (int ks = 0; ks < 2; ++ks)
      dst[i][ks] = *(const bf16x8_t*)&buf[(row0 + i*16 + fr)*64 + (((ks*4 + fg) ^ sw) << 3)];
}

// ---- one C-quadrant x K=64: 16 MFMA ----
template<int IB, int JB>
__device__ __forceinline__ void mquad(f32x4_t (&acc)[8][4],
                                      const bf16x8_t (&af)[4][2], const bf16x8_t (&bf)[2][2]) {
  #pragma unroll
  for (int ks = 0; ks < 2; ++ks)
    #pragma unroll
    for (int i = 0; i < 4; ++i)
      #pragma unroll
      for (int j = 0; j < 2; ++j)
        acc[IB+i][JB+j] = __builtin_amdgcn_mfma_f32_16x16x32_bf16(af[i][ks], bf[j][ks], acc[IB+i][JB+j], 0, 0, 0);
}

// ================= 256x256 GEMM, 2-barrier/K-tile, 2-deep counted-vmcnt prefetch ========
// C = alpha * A @ Bt^T (+bias)(+relu).  A:[M,K] bf16 (lda), Bt:[N,K] bf16 (ldb).
// 512 thr = 8 waves (2M x 4N), per-wave C 128x64. BK=64, 2-buffer 128KiB LDS, swizzled.
// Tile t: region1{ rd a0,b0; stage B0(t+1); quad00; rd a1,b1; stage B1(t+1); quad42 }
//         BARRIER  (all As[cur]/Bs[cur] reads consumed -> safe to overwrite As[cur])
//         region2{ stage A0(t+2); quad02; stage A1(t+2); vmcnt(4) }
//         BARRIER  (every wave passed its own vmcnt -> tile t+1 fully landed)
// vmcnt trace: after prologue 4 outstanding (A(t+1)); region1 +4 (B(t+1)); region2 +4
// (A(t+2)); vmcnt(4) -> oldest 8 = tile t+1 complete. Tail: vmcnt(0).
template<bool OUT_BF16, bool BIAS, bool RELU, bool CSKIP, bool CKLIM>
__global__ __launch_bounds__(512, 2)
void gemm256_kernel(const bf16_t* __restrict__ A,
                    const bf16_t* __restrict__ Bt,
                    const float* __restrict__ bias,
                    void* __restrict__ Cv,
                    int M, int N, int K,
                    int lda, int ldb, int ldc,
                    long long sA, long long sB, long long sBias,
                    int zshift, long long sC_hi, long long sC_lo,
                    int msub_shift, long long msub_stride,
                    float alpha)
{
  const int zb = blockIdx.z;
  const int m0 = blockIdx.x * 256;
  const int n0 = blockIdx.y * 256;
  if (CSKIP && n0 > m0 + 255) return;
  int kend = K;
  if (CKLIM) { int ke = m0 + 256; kend = ke < K ? ke : K; }
  const int nt = kend >> 6;

  const bf16_t* Az = A + (long long)zb * sA;
  const bf16_t* Bz = Bt + (long long)zb * sB;
  const long long coff = ((long long)(zb >> zshift)) * sC_hi
                       + ((long long)(zb & ((1 << zshift) - 1))) * sC_lo;

  __shared__ __align__(16) bf16_t As[2][256 * 64];
  __shared__ __align__(16) bf16_t Bs[2][256 * 64];

  const int tid = threadIdx.x;          // 0..511
  const int lane = tid & 63;
  const int w = tid >> 6;               // 0..7
  const int wm = (w >> 2) * 128;        // 0,128
  const int wn = (w & 3) * 64;          // 0,64,128,192
  const int fr = lane & 15;
  const int fg = lane >> 4;
  const int sw = fr & 7;

  // staging: thread -> row_local = (tid>>3), chunk (tid&7); swizzled global col
  const int srow = tid >> 3;            // 0..63
  const int scol8 = tid & 7;
  const int gswz = ((scol8 ^ (srow & 7)) << 3);

  f32x4_t acc[8][4];
  #pragma unroll
  for (int i = 0; i < 8; ++i)
    #pragma unroll
    for (int j = 0; j < 4; ++j)
      acc[i][j] = (f32x4_t){0.f, 0.f, 0.f, 0.f};

  const bf16_t* gA0 = Az + (long long)(m0 + srow) * lda + gswz;
  const bf16_t* gB0 = Bz + (long long)(n0 + srow) * ldb + gswz;

  // stage one 128x64 half-tile (2 global_load_lds/thread). h:0=A0,1=A1,2=B0,3=B1
  auto stage_half = [&](int buf, int kt, int h) {
    if (h < 2) {
      const bf16_t* g = gA0 + (long long)(h * 128) * lda + (kt << 6);
      bf16_t* l = &As[buf][(h*128 + srow) * 64 + (scol8 << 3)];
      __builtin_amdgcn_global_load_lds((const glb_u32*)g, (lds_u32*)l, 16, 0, 0);
      __builtin_amdgcn_global_load_lds((const glb_u32*)(g + 64LL*lda), (lds_u32*)(l + 64*64), 16, 0, 0);
    } else {
      const int hh = h - 2;
      const bf16_t* g = gB0 + (long long)(hh * 128) * ldb + (kt << 6);
      bf16_t* l = &Bs[buf][(hh*128 + srow) * 64 + (scol8 << 3)];
      __builtin_amdgcn_global_load_lds((const glb_u32*)g, (lds_u32*)l, 16, 0, 0);
      __builtin_amdgcn_global_load_lds((const glb_u32*)(g + 64LL*ldb), (lds_u32*)(l + 64*64), 16, 0, 0);
    }
  };

  // prologue: full t0 + A-halves of t1; wait t0 landed (allow A(t1)'s 4 loads in flight)
  stage_half(0, 0, 0); stage_half(0, 0, 1); stage_half(0, 0, 2); stage_half(0, 0, 3);
  if (nt > 1) { stage_half(1, 1, 0); stage_half(1, 1, 1); }
  if (nt > 1) asm volatile("s_waitcnt vmcnt(4)" ::: "memory");
  else        asm volatile("s_waitcnt vmcnt(0)" ::: "memory");
  __builtin_amdgcn_s_barrier();
  __builtin_amdgcn_sched_barrier(0);

  for (int t = 0; t < nt; ++t) {
    const int cur = t & 1;
    const bf16_t* Ac = &As[cur][0];
    const bf16_t* Bc = &Bs[cur][0];
    bf16x8_t a0[4][2], a1[4][2], b0[2][2], b1[2][2];

    // ---- region 1: all LDS reads of tile t + B-stages of t+1 (other buffer) ----
    ldsread<4>(Ac, wm, fr, fg, sw, a0);
    ldsread<2>(Bc, wn, fr, fg, sw, b0);
    if (t + 1 < nt) stage_half(cur ^ 1, t + 1, 2);
    mquad<0, 0>(acc, a0, b0);
    ldsread<4>(Ac, wm + 64, fr, fg, sw, a1);
    ldsread<2>(Bc, wn + 32, fr, fg, sw, b1);
    if (t + 1 < nt) stage_half(cur ^ 1, t + 1, 3);
    mquad<4, 2>(acc, a1, b1);

    __builtin_amdgcn_s_barrier();        // all reads of buf cur consumed
    __builtin_amdgcn_sched_barrier(0);

    // ---- region 2: register-only quads + A-stages of t+2 (into buf cur) ----
    if (t + 2 < nt) stage_half(cur, t + 2, 0);
    mquad<0, 2>(acc, a0, b1);
    if (t + 2 < nt) {
      stage_half(cur, t + 2, 1);
      asm volatile("s_waitcnt vmcnt(4)" ::: "memory");   // tile t+1 fully landed
    } else {
      asm volatile("s_waitcnt vmcnt(0)" ::: "memory");
    }
    mquad<4, 0>(acc, a1, b0);

    __builtin_amdgcn_s_barrier();        // collective: t+1 data visible to all
    __builtin_amdgcn_sched_barrier(0);
  }

  #pragma unroll
  for (int i = 0; i < 8; ++i) {
    #pragma unroll
    for (int e = 0; e < 4; ++e) {
      const int row = m0 + wm + i*16 + fg*4 + e;
      const long long ro = coff
        + ((long long)(row >> msub_shift)) * msub_stride
        + (long long)(row & ((1 << msub_shift) - 1)) * (long long)ldc;
      #pragma unroll
      for (int j = 0; j < 4; ++j) {
        const int col = n0 + wn + j*16 + fr;
        float v = acc[i][j][e] * alpha;
        if (BIAS) v += bias[(long long)zb * sBias + col];
        if (RELU) v = v > 0.f ? v : 0.f;
        if (OUT_BF16) ((bf16_t*)Cv)[ro + col] = (bf16_t)v;
        else          ((float*)Cv)[ro + col]  = v;
      }
    }
  }
}

// ================= 128x128 m97-style GEMM (kept for lm head, N=128) =================
template<bool OUT_BF16, bool BIAS, bool RELU, bool CSKIP, bool CKLIM>
__global__ __launch_bounds__(256, 4)
void gemm_bt_kernel(const bf16_t* __restrict__ A,
                    const bf16_t* __restrict__ Bt,
                    const float* __restrict__ bias,
                    void* __restrict__ Cv,
                    int M, int N, int K,
                    int lda, int ldb, int ldc,
                    long long sA, long long sB, long long sBias,
                    int zshift, long long sC_hi, long long sC_lo,
                    int msub_shift, long long msub_stride,
                    float alpha)
{
  const int zb = blockIdx.z;
  const int m0 = blockIdx.x * 128;
  const int n0 = blockIdx.y * 128;
  if (CSKIP && n0 > m0 + 127) return;
  int kend = K;
  if (CKLIM) { int ke = m0 + 128; kend = ke < K ? ke : K; }

  const bf16_t* Az = A + (long long)zb * sA;
  const bf16_t* Bz = Bt + (long long)zb * sB;
  const long long coff = ((long long)(zb >> zshift)) * sC_hi
                       + ((long long)(zb & ((1 << zshift) - 1))) * sC_lo;

  __shared__ __align__(16) bf16_t As[128 * 64];
  __shared__ __align__(16) bf16_t Bs[128 * 64];

  const int tid = threadIdx.x;
  const int wv = tid >> 6;
  const int lane = tid & 63;
  const int wm = (wv >> 1) * 64;
  const int wn = (wv & 1) * 64;
  const int fr = lane & 15;
  const int fg = lane >> 4;
  const int sw = fr & 7;

  f32x4_t acc[4][4];
  #pragma unroll
  for (int i = 0; i < 4; ++i)
    #pragma unroll
    for (int j = 0; j < 4; ++j)
      acc[i][j] = (f32x4_t){0.f, 0.f, 0.f, 0.f};

  const bf16_t* ga = Az + (long long)(m0 + (wv << 5) + (lane >> 3)) * lda
                   + (((lane & 7) ^ (lane >> 3)) << 3);
  const bf16_t* gb = Bz + (long long)(n0 + (wv << 5) + (lane >> 3)) * ldb
                   + (((lane & 7) ^ (lane >> 3)) << 3);

  for (int k0 = 0; k0 < kend; k0 += 64) {
    #pragma unroll
    for (int s = 0; s < 4; ++s) {
      __builtin_amdgcn_global_load_lds(
        (const glb_u32*)(ga + (long long)s * 8 * lda + k0),
        (lds_u32*)(As + (wv * 4 + s) * 512), 16, 0, 0);
      __builtin_amdgcn_global_load_lds(
        (const glb_u32*)(gb + (long long)s * 8 * ldb + k0),
        (lds_u32*)(Bs + (wv * 4 + s) * 512), 16, 0, 0);
    }
    __syncthreads();
    #pragma unroll
    for (int kc = 0; kc < 2; ++kc) {
      const int ca = ((kc * 4 + fg) ^ sw) << 3;
      bf16x8_t af[4], bfr[4];
      #pragma unroll
      for (int i = 0; i < 4; ++i)
        af[i] = *(const bf16x8_t*)&As[(wm + i*16 + fr) * 64 + ca];
      #pragma unroll
      for (int j = 0; j < 4; ++j)
        bfr[j] = *(const bf16x8_t*)&Bs[(wn + j*16 + fr) * 64 + ca];
      #pragma unroll
      for (int i = 0; i < 4; ++i)
        #pragma unroll
        for (int j = 0; j < 4; ++j)
          acc[i][j] = __builtin_amdgcn_mfma_f32_16x16x32_bf16(af[i], bfr[j], acc[i][j], 0, 0, 0);
    }
    __syncthreads();
  }

  #pragma unroll
  for (int i = 0; i < 4; ++i) {
    #pragma unroll
    for (int e = 0; e < 4; ++e) {
      const int row = m0 + wm + i*16 + fg*4 + e;
      const long long ro = coff
        + ((long long)(row >> msub_shift)) * msub_stride
        + (long long)(row & ((1 << msub_shift) - 1)) * (long long)ldc;
      #pragma unroll
      for (int j = 0; j < 4; ++j) {
        const int col = n0 + wn + j*16 + fr;
        float v = acc[i][j][e] * alpha;
        if (BIAS) v += bias[(long long)zb * sBias + col];
        if (RELU) v = v > 0.f ? v : 0.f;
        if (OUT_BF16) ((bf16_t*)Cv)[ro + col] = (bf16_t)v;
        else          ((float*)Cv)[ro + col]  = v;
      }
    }
  }
}

// ---------------- transpose (+cast to bf16): out[C][R] = in[R][C] ----------------
template<typename TIN>
__global__ void transpose_kernel(const TIN* __restrict__ in, bf16_t* __restrict__ out,
                                 int R, int C, long long sIn, long long sOut)
{
  __shared__ float tile[32][33];
  const long long zi = (long long)blockIdx.z * sIn;
  const long long zo = (long long)blockIdx.z * sOut;
  const int c0 = blockIdx.x * 32, r0 = blockIdx.y * 32;
  const int tx = threadIdx.x, ty = threadIdx.y;  // 32 x 8
  #pragma unroll
  for (int i = 0; i < 4; ++i) {
    int r = r0 + ty + i*8;
    tile[ty + i*8][tx] = (float)in[zi + (long long)r * C + c0 + tx];
  }
  __syncthreads();
  #pragma unroll
  for (int i = 0; i < 4; ++i) {
    int c = c0 + ty + i*8;
    out[zo + (long long)c * R + r0 + tx] = (bf16_t)tile[tx][ty + i*8];
  }
}

// ---------------- q/k/v weight transpose for one layer, z=0..11 ----------------
__global__ void qkvT_kernel(const float* __restrict__ wq, const float* __restrict__ wk,
                            const float* __restrict__ wv, bf16_t* __restrict__ out, int layer)
{
  __shared__ float tile[32][33];
  const int z = blockIdx.z, op = z >> 2, h = z & 3;
  const float* src = (op == 0 ? wq : op == 1 ? wk : wv)
                   + ((long long)layer * NHEAD + h) * HD * HD;
  bf16_t* dst = out + (long long)z * HD * HD;
  const int c0 = blockIdx.x * 32, r0 = blockIdx.y * 32;
  const int tx = threadIdx.x, ty = threadIdx.y;
  #pragma unroll
  for (int i = 0; i < 4; ++i)
    tile[ty + i*8][tx] = src[(long long)(r0 + ty + i*8) * HD + c0 + tx];
  __syncthreads();
  #pragma unroll
  for (int i = 0; i < 4; ++i)
    dst[(long long)(c0 + ty + i*8) * HD + r0 + tx] = (bf16_t)tile[tx][ty + i*8];
}

// ---------------- two-source f32 -> bf16 convert (out laid [a | b]) ----------------
__global__ void convert2_kernel(const float* __restrict__ a, const float* __restrict__ b,
                                bf16_t* __restrict__ out, long long n)
{
  long long i = (long long)blockIdx.x * blockDim.x + threadIdx.x;
  long long stride = (long long)gridDim.x * blockDim.x;
  for (; i < 2*n; i += stride)
    out[i] = (bf16_t)(i < n ? a[i] : b[i - n]);
}

// ---------------- diagnostic fill ----------------
__global__ void fill_kernel(float* __restrict__ out, long long n, float v)
{
  long long i = (long long)blockIdx.x * blockDim.x + threadIdx.x;
  long long stride = (long long)gridDim.x * blockDim.x;
  for (; i < n; i += stride) out[i] = v;
}

// ---------------- positions: pos = cumsum(mask) - 1 ----------------
__global__ void pos_kernel(const int* __restrict__ mask, float* __restrict__ pos)
{
  __shared__ float scn[S_LEN];
  const int b = blockIdx.x, t = threadIdx.x;
  scn[t] = (float)(mask[b * S_LEN + t] != 0);
  __syncthreads();
  for (int off = 1; off < S_LEN; off <<= 1) {
    float add = (t >= off) ? scn[t - off] : 0.f;
    __syncthreads();
    scn[t] += add;
    __syncthreads();
  }
  pos[b * S_LEN + t] = scn[t] - 1.0f;
}

// ---------------- embedding + positional encoding ----------------
__global__ void embed_kernel(const int* __restrict__ ids, const int* __restrict__ mask,
                             const float* __restrict__ pos, const float* __restrict__ emb,
                             float* __restrict__ x, bf16_t* __restrict__ xb)
{
  const int idx = blockIdx.x * 256 + threadIdx.x;
  const int i = idx & 255;
  const int bs = idx >> 8;
  const int id = ids[bs];
  const float m = (float)(mask[bs] != 0);
  const float p = pos[bs];
  const float dv = __expf(-(float)(2 * i) * (9.210340371976184f / (float)HD));
  const float sv = __sinf(p * dv) * m;
  const float e0 = emb[id * HD + 2*i], e1 = emb[id * HD + 2*i + 1];
  const float x0 = e0 + sv, x1 = e1 + sv;
  x[(long long)bs * HD + 2*i]     = x0;
  x[(long long)bs * HD + 2*i + 1] = x1;
  xb[(long long)bs * HD + 2*i]     = (bf16_t)x0;
  xb[(long long)bs * HD + 2*i + 1] = (bf16_t)x1;
}

// ---------------- softmax: ONE WAVE PER ROW, bf16 in-place, pure shfl reduce ----------------
__global__ void softmax_kernel(bf16_t* __restrict__ scP,
                               const int* __restrict__ mask, int pair0)
{
  const int lane = threadIdx.x & 63;
  const int s = blockIdx.x * 4 + (threadIdx.x >> 6);
  const int pz = blockIdx.y;
  const int b = (pair0 + pz) >> 2;
  bf16_t* row = scP + ((long long)pz * S_LEN + s) * S_LEN;
  const int t0 = lane * 16;

  bf16x8_t r0 = *(const bf16x8_t*)&row[t0];
  bf16x8_t r1 = *(const bf16x8_t*)&row[t0 + 8];
  int4 m4[4];
  #pragma unroll
  for (int q = 0; q < 4; ++q) m4[q] = *(const int4*)&mask[b * S_LEN + t0 + q*4];
  const int* mm = (const int*)m4;

  float v[16]; bool ok[16];
  #pragma unroll
  for (int j = 0; j < 16; ++j) {
    const int t = t0 + j;
    ok[j] = (t <= s) && (mm[j] != 0);
    float raw = (j < 8) ? (float)r0[j] : (float)r1[j - 8];
    v[j] = ok[j] ? raw : -INFINITY;
  }
  float mx = v[0];
  #pragma unroll
  for (int j = 1; j < 16; ++j) mx = fmaxf(mx, v[j]);
  #pragma unroll
  for (int o = 32; o; o >>= 1) mx = fmaxf(mx, __shfl_xor(mx, o));

  float e[16]; float sum = 0.f;
  #pragma unroll
  for (int j = 0; j < 16; ++j) { e[j] = ok[j] ? __expf(v[j] - mx) : 0.f; sum += e[j]; }
  #pragma unroll
  for (int o = 32; o; o >>= 1) sum += __shfl_xor(sum, o);

  const bool qvalid = mask[b * S_LEN + s] != 0;
  const float inv = (qvalid && sum > 0.f) ? 1.f / sum : 0.f;
  bf16x8_t o0, o1;
  #pragma unroll
  for (int j = 0; j < 8; ++j) { o0[j] = (bf16_t)(e[j] * inv); o1[j] = (bf16_t)(e[j+8] * inv); }
  *(bf16x8_t*)&row[t0] = o0;
  *(bf16x8_t*)&row[t0 + 8] = o1;
}

// ---------------- layernorm: ONE WAVE PER ROW, float4 loads, pure shfl reduce ----------------
__global__ void ln_kernel(float* __restrict__ x, const float* __restrict__ tparts,
                          int ns, long long pstride,
                          const float* __restrict__ bias,
                          const float* __restrict__ g, const float* __restrict__ b,
                          bf16_t* __restrict__ xb)
{
  const int lane = threadIdx.x & 63;
  const long long row = (long long)blockIdx.x * 4 + (threadIdx.x >> 6);
  const int e0 = lane * 8;
  const long long base = row * HD + e0;

  float4 xa = *(const float4*)&x[base];
  float4 xc = *(const float4*)&x[base + 4];
  float4 ba = *(const float4*)&bias[e0];
  float4 bc = *(const float4*)&bias[e0 + 4];
  float v[8] = {xa.x+ba.x, xa.y+ba.y, xa.z+ba.z, xa.w+ba.w,
                xc.x+bc.x, xc.y+bc.y, xc.z+bc.z, xc.w+bc.w};
  for (int i = 0; i < ns; ++i) {
    float4 p0 = *(const float4*)&tparts[i*pstride + base];
    float4 p1 = *(const float4*)&tparts[i*pstride + base + 4];
    v[0]+=p0.x; v[1]+=p0.y; v[2]+=p0.z; v[3]+=p0.w;
    v[4]+=p1.x; v[5]+=p1.y; v[6]+=p1.z; v[7]+=p1.w;
  }
  float s = 0.f;
  #pragma unroll
  for (int j = 0; j < 8; ++j) s += v[j];
  #pragma unroll
  for (int o = 32; o; o >>= 1) s += __shfl_xor(s, o);
  const float mu = s * (1.f / (float)HD);
  float q = 0.f;
  #pragma unroll
  for (int j = 0; j < 8; ++j) { v[j] -= mu; q += v[j]*v[j]; }
  #pragma unroll
  for (int o = 32; o; o >>= 1) q += __shfl_xor(q, o);
  const float inv = rsqrtf(q * (1.f / (float)HD) + 1e-5f);

  float4 ga4 = *(const float4*)&g[e0];
  float4 gc4 = *(const float4*)&g[e0 + 4];
  float4 bb4 = *(const float4*)&b[e0];
  float4 bd4 = *(const float4*)&b[e0 + 4];
  float y[8] = {v[0]*inv*ga4.x+bb4.x, v[1]*inv*ga4.y+bb4.y, v[2]*inv*ga4.z+bb4.z, v[3]*inv*ga4.w+bb4.w,
                v[4]*inv*gc4.x+bd4.x, v[5]*inv*gc4.y+bd4.y, v[6]*inv*gc4.z+bd4.z, v[7]*inv*gc4.w+bd4.w};
  *(float4*)&x[base]     = (float4){y[0],y[1],y[2],y[3]};
  *(float4*)&x[base + 4] = (float4){y[4],y[5],y[6],y[7]};
  bf16x8_t yb;
  #pragma unroll
  for (int j = 0; j < 8; ++j) yb[j] = (bf16_t)y[j];
  *(bf16x8_t*)&xb[base] = yb;
}

extern "C" void kernel_launch(void* const* d_in, const int* in_sizes, int n_in,
                              void* d_out, int out_size, void* d_ws, size_t ws_size,
                              hipStream_t stream)
{
  (void)in_sizes; (void)n_in;
  const int*   ids   = (const int*)d_in[0];
  const int*   amask = (const int*)d_in[1];
  const float* emb   = (const float*)d_in[2];
  const float* wq    = (const float*)d_in[3];
  const float* wk    = (const float*)d_in[4];
  const float* wv    = (const float*)d_in[5];
  const float* wo_w  = (const float*)d_in[6];
  const float* wo_b  = (const float*)d_in[7];
  const float* ln1_g = (const float*)d_in[8];
  const float* ln1_b = (const float*)d_in[9];
  const float* ff1_w = (const float*)d_in[10];
  const float* ff1_b = (const float*)d_in[11];
  const float* ff2_w = (const float*)d_in[12];
  const float* ff2_b = (const float*)d_in[13];
  const float* ln2_g = (const float*)d_in[14];
  const float* ln2_b = (const float*)d_in[15];
  const float* lm_w  = (const float*)d_in[16];

  const long long MROW = (long long)BATCH * S_LEN;   // 8192
  const size_t MBc = 1ull << 20;
  char* p = (char*)d_ws;
  auto alloc = [&](size_t bytes) { char* r = p; p += (bytes + 255) & ~(size_t)255; return r; };

  // persistent (~68 MB)
  float*  x     = (float*) alloc(MROW * HD * 4);                // 16 MB
  bf16_t* xb    = (bf16_t*)alloc(MROW * HD * 2);                // 8 MB
  bf16_t* ob    = (bf16_t*)alloc(MROW * (NHEAD*HD) * 2);        // 32 MB
  bf16_t* wqkvT = (bf16_t*)alloc(12LL * HD * HD * 2);           // 6 MB
  bf16_t* woT   = (bf16_t*)alloc((long long)HD * FFD * 2);      // 2 MB
  bf16_t* wff1  = (bf16_t*)alloc((long long)FFD * HD * 2);      // 2 MB
  bf16_t* wff2  = (bf16_t*)alloc((long long)HD * FFD * 2);      // 2 MB
  bf16_t* lmT   = (bf16_t*)alloc((long long)NTOK * HD * 2);
  float*  pos   = (float*) alloc(MROW * 4);

  const size_t used = (size_t)(p - (char*)d_ws);
  const size_t rem  = ws_size > used ? ws_size - used : 0;

  // tiers: attn region P*(q1+k1+vT1)MB + P*2MB scores;  FF region SK*16+32 MB (aliased)
  int P = 0, SK = 2;
  if      (rem >= 160 * MBc) { P = 32; SK = 4; }  // attn 160 MB, FF 96 MB
  else if (rem >= 64 * MBc)  { P = 8;  SK = 2; }  // attn 40 MB, FF 64 MB
  if (P == 0) {
    fill_kernel<<<1024, 256, 0, stream>>>((float*)d_out, (long long)out_size,
                                          (float)(ws_size >> 20));
    return;
  }

  char* A = p;
  const long long pairE = (long long)S_LEN * HD;
  bf16_t* qc  = (bf16_t*)A;
  bf16_t* kc  = qc  + (long long)P * pairE;
  bf16_t* vTc = kc  + (long long)P * pairE;
  bf16_t* scb = vTc + (long long)P * pairE;        // bf16 scores, softmax in-place
  float*  tmp = (float*)A;                          // FF phase aliases (SK partials)
  bf16_t* ffb = (bf16_t*)(A + (size_t)SK * 16 * MBc);

  const dim3 tb(32, 8);
  transpose_kernel<float><<<dim3(4,16,1), tb, 0, stream>>>(lm_w, lmT, HD, NTOK, 0, 0);
  pos_kernel<<<BATCH, S_LEN, 0, stream>>>(amask, pos);
  embed_kernel<<<8192, 256, 0, stream>>>(ids, amask, pos, emb, x, xb);

  const int nch = 32 / P;
  const int bpc = P / NHEAD;

  for (int l = 0; l < NBLK; ++l) {
    qkvT_kernel<<<dim3(16,16,12), tb, 0, stream>>>(wq, wk, wv, wqkvT, l);
    transpose_kernel<float><<<dim3(16,64,1), tb, 0, stream>>>(
      wo_w + (long long)l*FFD*HD, woT, FFD, HD, 0, 0);
    convert2_kernel<<<2048, 256, 0, stream>>>(
      ff1_w + (long long)l*FFD*HD, ff2_w + (long long)l*HD*FFD, wff1, (long long)FFD*HD);

    for (int c = 0; c < nch; ++c) {
      const int b0 = c * bpc;
      const int pair0 = b0 * NHEAD;
      const int Mch = bpc * S_LEN;

      // fused q/k projections: z = op*4 + head (op in {q,k})
      gemm256_kernel<true,false,false,false,false><<<dim3(Mch/256,2,8),512,0,stream>>>(
        xb + (long long)b0*S_LEN*HD, wqkvT, nullptr, qc, Mch, HD, HD, HD, HD, HD,
        0, (long long)HD*HD, 0,
        2, (long long)P*pairE, (long long)S_LEN*HD,
        10, (long long)NHEAD*S_LEN*HD, 1.f);

      // direct vT projection: vT[pair][d][t] = sum_h wvT[head][d][h] * xb[b,t,h]
      gemm256_kernel<true,false,false,false,false><<<dim3(8,4,bpc),512,0,stream>>>(
        wqkvT + 8LL*HD*HD, xb + (long long)b0*S_LEN*HD, nullptr, vTc,
        2048, S_LEN, HD, HD, HD, S_LEN,
        0, (long long)S_LEN*HD, 0,
        0, (long long)NHEAD*HD*S_LEN, 0,
        9, (long long)HD*S_LEN, 1.f);

      // scores = q @ k^T / sqrt(512) -> bf16 scb (causal tile skip)
      gemm256_kernel<true,false,false,true,false><<<dim3(4,4,P),512,0,stream>>>(
        qc, kc, nullptr, scb,
        S_LEN, S_LEN, HD, HD, HD, S_LEN,
        (long long)S_LEN*HD, (long long)S_LEN*HD, 0,
        30, 0, (long long)S_LEN*S_LEN,
        30, 0, 0.044194173824159216f);
      softmax_kernel<<<dim3(S_LEN/4,P),256,0,stream>>>(scb, amask, pair0);
      // o = P @ v   (causal k-limit)
      gemm256_kernel<true,false,false,false,true><<<dim3(4,2,P),512,0,stream>>>(
        scb, vTc, nullptr,
        ob + (long long)b0*S_LEN*(NHEAD*HD),
        S_LEN, HD, S_LEN, S_LEN, S_LEN, NHEAD*HD,
        (long long)S_LEN*S_LEN, (long long)HD*S_LEN, 0,
        2, (long long)S_LEN*NHEAD*HD, HD,
        30, 0, 1.f);
    }

    // mh = o @ wo (split-K=SK -> tmp partials; bias folded into LN)
    gemm256_kernel<false,false,false,false,false><<<dim3(32,2,SK),512,0,stream>>>(
      ob, woT, nullptr, tmp,
      (int)MROW, HD, (NHEAD*HD)/SK, NHEAD*HD, NHEAD*HD, HD,
      (NHEAD*HD)/SK, (NHEAD*HD)/SK, 0,
      0, (long long)MROW*HD, 0,
      30, 0, 1.f);
    ln_kernel<<<2048,256,0,stream>>>(x, tmp, SK, (long long)MROW*HD,
                                     wo_b + l*HD, ln1_g + l*HD, ln1_b + l*HD, xb);

    // ff1: relu(xb @ ff1^T + b1) -> ffb (bf16)
    gemm256_kernel<true,true,true,false,false><<<dim3(32,8,1),512,0,stream>>>(
      xb, wff1, ff1_b + l*FFD, ffb,
      (int)MROW, FFD, HD, HD, HD, FFD,
      0, 0, 0, 30, 0, 0, 30, 0, 1.f);
    // ff2 (split-K=SK)
    gemm256_kernel<false,false,false,false,false><<<dim3(32,2,SK),512,0,stream>>>(
      ffb, wff2, nullptr, tmp,
      (int)MROW, HD, FFD/SK, FFD, FFD, HD,
      FFD/SK, FFD/SK, 0,
      0, (long long)MROW*HD, 0,
      30, 0, 1.f);
    ln_kernel<<<2048,256,0,stream>>>(x, tmp, SK, (long long)MROW*HD,
                                     ff2_b + l*HD, ln2_g + l*HD, ln2_b + l*HD, xb);
  }

  // lm head -> d_out (f32), N=128 -> 128-tile kernel
  gemm_bt_kernel<false,false,false,false,false><<<dim3(64,1,1),256,0,stream>>>(
    xb, lmT, nullptr, (float*)d_out,
    (int)MROW, NTOK, HD, HD, HD, NTOK,
    0, 0, 0, 30, 0, 0, 30, 0, 1.f);
}